// Round 6
// baseline (452.225 us; speedup 1.0000x reference)
//
#include <hip/hip_runtime.h>
#include <hip/hip_bf16.h>

typedef unsigned short u16;
typedef unsigned int   u32;
typedef short short8 __attribute__((ext_vector_type(8)));
typedef float f32x4  __attribute__((ext_vector_type(4)));

// ---------- bf16 helpers ----------
__device__ __forceinline__ float b2f(u16 u) { return __uint_as_float(((u32)u) << 16); }
__device__ __forceinline__ u16 f2b(float f) {
    u32 u = __float_as_uint(f);
    u += 0x7FFF + ((u >> 16) & 1);   // RTNE
    return (u16)(u >> 16);
}
// fast gelu (tanh form), |err| < 4e-4 (far below bf16 storage rounding)
__device__ __forceinline__ float gelu_fast(float v) {
    float a = v * (2.302118f + 0.102953f * v * v);   // 2*log2e*0.79788456*(1+0.044715 v^2)
    a = fminf(a, 120.f);                              // avoid inf/inf for v > ~10.8
    float e = exp2f(a);
    return v * e / (1.f + e);
}

// ---------- async global->LDS 16B (wave-uniform LDS base + lane*16) ----------
typedef const unsigned int __attribute__((address_space(1)))* gas1;
typedef unsigned int __attribute__((address_space(3)))* las3;
__device__ __forceinline__ void async_ld16(const void* g, const void* l) {
    __builtin_amdgcn_global_load_lds((gas1)(unsigned long long)g,
                                     (las3)(unsigned int)(unsigned long long)l,
                                     16, 0, 0);
}

// ================= fused prep: 7x wtrans + xPos table + LN1 =================
__device__ __forceinline__ void wtrans_body(const float* __restrict__ W, u16* __restrict__ Wt,
                                            int K, int N, int bx, int by, int bz) {
    __shared__ u16 tile[32][36];
    const int k0 = bx * 32, n0 = by * 32;
    const float* Wz = W + (long)bz * K * N;
    u16* Wtz = Wt + (long)bz * K * N;
    const int t = threadIdx.x;
    const int r = t >> 3, c = (t & 7) * 4;
    float4 v = *(const float4*)(Wz + (long)(k0 + r) * N + n0 + c);
    tile[r][c+0] = f2b(v.x); tile[r][c+1] = f2b(v.y);
    tile[r][c+2] = f2b(v.z); tile[r][c+3] = f2b(v.w);
    __syncthreads();
    uint2 pk;
    pk.x = (u32)tile[c+0][r] | ((u32)tile[c+1][r] << 16);
    pk.y = (u32)tile[c+2][r] | ((u32)tile[c+3][r] << 16);
    *(uint2*)(Wtz + (long)(n0 + r) * K + k0 + c) = pk;
}

__device__ __forceinline__ void xtab_body(float4* __restrict__ tab, int blk) {
    int idx = blk * 256 + threadIdx.x;   // 0..131071
    int j = idx & 63, s = idx >> 6;
    float sv = (2.f * j + 51.2f) / 179.2f;
    float scale = exp2f(log2f(sv) * ((float)s * (1.f / 512.f)));
    float inv_freq = exp2f((float)j * (-13.287712379549449f / 64.f));
    float ang = (float)s * inv_freq;
    float sn = sinf(ang), cs = cosf(ang);
    tab[idx] = make_float4(cs * scale, sn * scale, cs / scale, sn / scale);
}

__device__ __forceinline__ void ln_body(const float* __restrict__ X,
                                        const float* __restrict__ w,
                                        const float* __restrict__ bb,
                                        u16* __restrict__ out, long row) {
    const int t = threadIdx.x;
    float4 p = ((const float4*)(X + row * 1024))[t];
    float x[4] = { p.x, p.y, p.z, p.w };
    float s = x[0]+x[1]+x[2]+x[3];
    float q = x[0]*x[0]+x[1]*x[1]+x[2]*x[2]+x[3]*x[3];
#pragma unroll
    for (int o = 32; o > 0; o >>= 1) { s += __shfl_down(s, o, 64); q += __shfl_down(q, o, 64); }
    __shared__ float aS[4], aQ[4];
    if ((t & 63) == 0) { aS[t >> 6] = s; aQ[t >> 6] = q; }
    __syncthreads();
    s = aS[0]+aS[1]+aS[2]+aS[3];
    q = aQ[0]+aQ[1]+aQ[2]+aQ[3];
    float mean = s * (1.f/1024.f);
    float var  = q * (1.f/1024.f) - mean*mean;
    float rstd = rsqrtf(var + 1e-5f);
    float4 wv = ((const float4*)w)[t];
    float4 bv = ((const float4*)bb)[t];
    uint2 r;
    r.x = (u32)f2b((x[0]-mean)*rstd*wv.x + bv.x) | ((u32)f2b((x[1]-mean)*rstd*wv.y + bv.y) << 16);
    r.y = (u32)f2b((x[2]-mean)*rstd*wv.z + bv.z) | ((u32)f2b((x[3]-mean)*rstd*wv.w + bv.w) << 16);
    ((uint2*)(out + row * 1024))[t] = r;
}

__global__ __launch_bounds__(256) void prep_k(
    const float* __restrict__ Wq, const float* __restrict__ Wk,
    const float* __restrict__ Wv, const float* __restrict__ WG,
    const float* __restrict__ WO, const float* __restrict__ fw1,
    const float* __restrict__ fw2, const float* __restrict__ X,
    const float* __restrict__ ln1w, const float* __restrict__ ln1b,
    u16* __restrict__ WT, u16* __restrict__ WOT,
    u16* __restrict__ fw1T, u16* __restrict__ fw2T,
    float4* __restrict__ xtab, u16* __restrict__ Xn) {
    const int id = blockIdx.x;
    if (id < 16384) {
        const float* W; u16* Wt; int K, N, bx, by, bz = 0;
        if (id < 1024)       { W=Wq;  Wt=WT;           K=1024; N=128;  int l=id;       bx=l&31;  by=(l>>5)&3; bz=l>>7; }
        else if (id < 2048)  { W=Wk;  Wt=WT+1048576;   K=1024; N=128;  int l=id-1024;  bx=l&31;  by=(l>>5)&3; bz=l>>7; }
        else if (id < 4096)  { W=Wv;  Wt=WT+2097152;   K=1024; N=256;  int l=id-2048;  bx=l&31;  by=(l>>5)&7; bz=l>>8; }
        else if (id < 6144)  { W=WG;  Wt=WT+4194304;   K=1024; N=2048; int l=id-4096;  bx=l&31;  by=l>>5; }
        else if (id < 8192)  { W=WO;  Wt=WOT;          K=2048; N=1024; int l=id-6144;  bx=l&63;  by=l>>6; }
        else if (id < 12288) { W=fw1; Wt=fw1T;         K=1024; N=4096; int l=id-8192;  bx=l&31;  by=l>>5; }
        else                 { W=fw2; Wt=fw2T;         K=4096; N=1024; int l=id-12288; bx=l&127; by=l>>7; }
        wtrans_body(W, Wt, K, N, bx, by, bz);
    } else if (id < 16896) {
        xtab_body(xtab, id - 16384);
    } else {
        ln_body(X, ln1w, ln1b, Xn, id - 16896);
    }
}

// ---------- combine WO partials + residual X, then LN2 ----------
// writes: dinit = X2 + fb2 (fp32, pre-init for FFN2 atomic accumulation)
//         hb    = LN2(X2)  (bf16, FFN1 input)
__global__ __launch_bounds__(256) void ln2_combine(const float* __restrict__ P,
                                                   const float* __restrict__ X,
                                                   const float* __restrict__ w,
                                                   const float* __restrict__ bb,
                                                   const float* __restrict__ fb2,
                                                   float* __restrict__ dinit,
                                                   u16* __restrict__ hb) {
    const long row = blockIdx.x;
    const int t = threadIdx.x;
    const float* p = P + row * 3072;
    float4 a = ((const float4*)p)[t];
    float4 c = ((const float4*)(p + 1024))[t];
    float4 xr = ((const float4*)(X + row * 1024))[t];
    float x[4] = { a.x+c.x+xr.x, a.y+c.y+xr.y, a.z+c.z+xr.z, a.w+c.w+xr.w };
    float4 b2 = ((const float4*)fb2)[t];
    ((float4*)(dinit + row * 1024))[t] = make_float4(
        x[0] + b2.x, x[1] + b2.y, x[2] + b2.z, x[3] + b2.w);
    float s = x[0]+x[1]+x[2]+x[3];
    float q = x[0]*x[0]+x[1]*x[1]+x[2]*x[2]+x[3]*x[3];
#pragma unroll
    for (int o = 32; o > 0; o >>= 1) { s += __shfl_down(s, o, 64); q += __shfl_down(q, o, 64); }
    __shared__ float aS[4], aQ[4];
    if ((t & 63) == 0) { aS[t >> 6] = s; aQ[t >> 6] = q; }
    __syncthreads();
    s = aS[0]+aS[1]+aS[2]+aS[3];
    q = aQ[0]+aQ[1]+aQ[2]+aQ[3];
    float mean = s * (1.f/1024.f);
    float var  = q * (1.f/1024.f) - mean*mean;
    float rstd = rsqrtf(var + 1e-5f);
    float4 wv = ((const float4*)w)[t];
    float4 bv = ((const float4*)bb)[t];
    uint2 r;
    r.x = (u32)f2b((x[0]-mean)*rstd*wv.x + bv.x) | ((u32)f2b((x[1]-mean)*rstd*wv.y + bv.y) << 16);
    r.y = (u32)f2b((x[2]-mean)*rstd*wv.z + bv.z) | ((u32)f2b((x[3]-mean)*rstd*wv.w + bv.w) << 16);
    ((uint2*)(hb + row * 1024))[t] = r;
}

// ---------- MFMA GEMM, templated panel count (BK = PANELS*32) ----------
// C = A[M][K] @ Bt[N][K]^T, bf16->fp32->bf16. mb innermost (mb = pid & 31), M=4096.
// EPI_QKVG: rotary for c<2048 (via xtab in `bias`); V-range blocks (2048<=col0<4096)
// store DIRECTLY TRANSPOSED into Vt (B,H,256,S) and skip the row-major write.
enum { EPI_GELU_BIAS = 2, EPI_QKVG = 4 };

template<int EPI, int PANELS>
__global__ __launch_bounds__(256) void mgemm(
    const u16* __restrict__ A, const u16* __restrict__ Bt, u16* __restrict__ Cv,
    int K, int aStride, long cStride,
    const float* __restrict__ bias, u16* __restrict__ Vt) {
    __shared__ __align__(16) u16 As[PANELS * 4096];
    __shared__ __align__(16) u16 Bs[PANELS * 4096];
    const int pid = blockIdx.x;
    const int mb = pid & 31;
    const int nb = pid >> 5;
    const int t = threadIdx.x;
    const int row0 = mb * 128, col0 = nb * 128;
    const int wave = t >> 6, lane = t & 63;
    const int wm = wave >> 1, wn = wave & 1;
    const int quad = lane >> 4, l16 = lane & 15;
    const u16* Ag = A + (long)(row0 + (t >> 2)) * aStride + ((t & 3) * 8);
    const u16* Bg = Bt + (long)(col0 + (t >> 2)) * K + ((t & 3) * 8);
    const long aj = (long)64 * aStride;
    const long bj = (long)64 * K;
    const u32 lo = __builtin_amdgcn_readfirstlane((u32)(wave * 1024));

    f32x4 acc[4][4];
#pragma unroll
    for (int i = 0; i < 4; i++)
#pragma unroll
        for (int j = 0; j < 4; j++) acc[i][j] = (f32x4){0.f, 0.f, 0.f, 0.f};

    for (int k0 = 0; k0 < K; k0 += PANELS * 32) {
#pragma unroll
        for (int h = 0; h < PANELS; h++) {
            const u16* Agh = Ag + k0 + h * 32;
            const u16* Bgh = Bg + k0 + h * 32;
            async_ld16(Agh,      (const char*)As + h*8192 + lo);
            async_ld16(Agh + aj, (const char*)As + h*8192 + 4096 + lo);
            async_ld16(Bgh,      (const char*)Bs + h*8192 + lo);
            async_ld16(Bgh + bj, (const char*)Bs + h*8192 + 4096 + lo);
        }
        __syncthreads();
#pragma unroll
        for (int h = 0; h < PANELS; h++) {
            short8 af[4], bf[4];
#pragma unroll
            for (int mt = 0; mt < 4; mt++)
                af[mt] = *(const short8*)(As + h*4096 + (wm*64 + mt*16 + l16) * 32 + quad*8);
#pragma unroll
            for (int nt = 0; nt < 4; nt++)
                bf[nt] = *(const short8*)(Bs + h*4096 + (wn*64 + nt*16 + l16) * 32 + quad*8);
#pragma unroll
            for (int mt = 0; mt < 4; mt++)
#pragma unroll
                for (int nt = 0; nt < 4; nt++)
                    acc[mt][nt] = __builtin_amdgcn_mfma_f32_16x16x32_bf16(af[mt], bf[nt], acc[mt][nt], 0, 0, 0);
        }
        __syncthreads();
    }

    if constexpr (EPI == EPI_QKVG) {
        if (col0 >= 2048 && col0 < 4096) {
            // V blocks: store transposed into Vt (B,H,256,S). reg 0..3 = 4 consecutive s.
            const int bq = row0 >> 11;
            const int sb = (row0 & 2047) + wm*64 + quad*4;
#pragma unroll
            for (int mt = 0; mt < 4; mt++) {
#pragma unroll
                for (int nt = 0; nt < 4; nt++) {
                    int vc = (col0 - 2048) + wn*64 + nt*16 + l16;
                    u16* dst = Vt + ((long)((bq << 3) + (vc >> 8)) * 256 + (vc & 255)) * 2048
                                  + sb + mt*16;
                    uint2 pk;
                    pk.x = (u32)f2b(acc[mt][nt][0]) | ((u32)f2b(acc[mt][nt][1]) << 16);
                    pk.y = (u32)f2b(acc[mt][nt][2]) | ((u32)f2b(acc[mt][nt][3]) << 16);
                    *(uint2*)dst = pk;
                }
            }
            return;
        }
    }

#pragma unroll
    for (int mt = 0; mt < 4; mt++) {
#pragma unroll
        for (int reg = 0; reg < 4; reg++) {
            int r = row0 + wm*64 + mt*16 + quad*4 + reg;
#pragma unroll
            for (int nt = 0; nt < 4; nt++) {
                int c = col0 + wn*64 + nt*16 + l16;
                float v = acc[mt][nt][reg];
                if constexpr (EPI == EPI_GELU_BIAS) {
                    v = gelu_fast(v + bias[c]);
                } else if constexpr (EPI == EPI_QKVG) {
                    if (c < 2048) {  // xPos rotary: Q (c<1024, up) / K (else, down) via table
                        int j = (c & 127) >> 1;
                        float4 tb = ((const float4*)bias)[((r & 2047) << 6) + j];
                        float cs = (c < 1024) ? tb.x : tb.z;
                        float sn = (c < 1024) ? tb.y : tb.w;
                        float partner = __shfl_xor(v, 1, 64);
                        v = v * cs + ((c & 1) ? partner : -partner) * sn;
                    }
                }
                Cv[(long)r * cStride + c] = f2b(v);
            }
        }
    }
}

// ---------- split-K (x2) MFMA GEMM, BK=64 paneled, N=1024, fp32 partial out ----------
// ATOMIC=0: write partials to P + slice*sliceOff (row stride pRowStride).
// ATOMIC=1: atomicAdd into pre-initialized P (both slices same target; sliceOff=0).
template<int ATOMIC>
__global__ __launch_bounds__(256) void mgemm_sk(
    const u16* __restrict__ A, const u16* __restrict__ Bt, float* __restrict__ P,
    int K, int kHalf, int aStride, long pRowStride, long sliceOff) {
    __shared__ __align__(16) u16 As[2 * 4096];
    __shared__ __align__(16) u16 Bs[2 * 4096];
    const int pid = blockIdx.x;
    const int mb = pid & 31;
    const int nb = (pid & 255) >> 5;
    const int slice = pid >> 8;
    const int t = threadIdx.x;
    const int row0 = mb * 128, col0 = nb * 128;
    const int wave = t >> 6, lane = t & 63;
    const int wm = wave >> 1, wn = wave & 1;
    const int quad = lane >> 4, l16 = lane & 15;
    const u16* Ag = A + (long)(row0 + (t >> 2)) * aStride + ((t & 3) * 8);
    const u16* Bg = Bt + (long)(col0 + (t >> 2)) * K + ((t & 3) * 8);
    const long aj = (long)64 * aStride;
    const long bj = (long)64 * K;
    const u32 lo = __builtin_amdgcn_readfirstlane((u32)(wave * 1024));

    f32x4 acc[4][4];
#pragma unroll
    for (int i = 0; i < 4; i++)
#pragma unroll
        for (int j = 0; j < 4; j++) acc[i][j] = (f32x4){0.f, 0.f, 0.f, 0.f};

    const int kBeg = slice * kHalf, kEnd = kBeg + kHalf;
    for (int k0 = kBeg; k0 < kEnd; k0 += 64) {
#pragma unroll
        for (int h = 0; h < 2; h++) {
            const u16* Agh = Ag + k0 + h * 32;
            const u16* Bgh = Bg + k0 + h * 32;
            async_ld16(Agh,      (const char*)As + h*8192 + lo);
            async_ld16(Agh + aj, (const char*)As + h*8192 + 4096 + lo);
            async_ld16(Bgh,      (const char*)Bs + h*8192 + lo);
            async_ld16(Bgh + bj, (const char*)Bs + h*8192 + 4096 + lo);
        }
        __syncthreads();
#pragma unroll
        for (int h = 0; h < 2; h++) {
            short8 af[4], bf[4];
#pragma unroll
            for (int mt = 0; mt < 4; mt++)
                af[mt] = *(const short8*)(As + h*4096 + (wm*64 + mt*16 + l16) * 32 + quad*8);
#pragma unroll
            for (int nt = 0; nt < 4; nt++)
                bf[nt] = *(const short8*)(Bs + h*4096 + (wn*64 + nt*16 + l16) * 32 + quad*8);
#pragma unroll
            for (int mt = 0; mt < 4; mt++)
#pragma unroll
                for (int nt = 0; nt < 4; nt++)
                    acc[mt][nt] = __builtin_amdgcn_mfma_f32_16x16x32_bf16(af[mt], bf[nt], acc[mt][nt], 0, 0, 0);
        }
        __syncthreads();
    }

    float* Pb = P + slice * sliceOff;
#pragma unroll
    for (int mt = 0; mt < 4; mt++) {
#pragma unroll
        for (int reg = 0; reg < 4; reg++) {
            int r = row0 + wm*64 + mt*16 + quad*4 + reg;
#pragma unroll
            for (int nt = 0; nt < 4; nt++) {
                int c = col0 + wn*64 + nt*16 + l16;
                if constexpr (ATOMIC) {
                    atomicAdd(&Pb[(long)r * pRowStride + c], acc[mt][nt][reg]);
                } else {
                    Pb[(long)r * pRowStride + c] = acc[mt][nt][reg];
                }
            }
        }
    }
}

// ---------- MFMA retention + fused groupnorm + fused silu-gate ----------
// grid 512 (1D). QKVG (B,S,6144): Q cols 0..1023, K 1024..2047, G 4096..6143.
// Writes gated = silu(G)*groupnorm(O) in-place over the G segment. Vt (B,H,256,S).
// T2/T21 swizzle on Qs/Ks/Vs: 64-B rows (4x 16B slots) put all fragment reads at
// 8-way bank conflict (bank = l16*16+quad*4 mod 32 -> 2 banks/16 lanes). Fix:
// read slot = quad ^ (l16&3) ^ ((l16>>2)&3)  (2-way = free, m136); staged content
// pre-permuted via global source column cb ^ ((c>>2)&3) ^ ((c>>4)&3)  (LDS flat
// index = 8c for all three staging paths, so row bits of c match read-row bits).
__global__ __launch_bounds__(256) void retention_mfma(
    u16* __restrict__ QKVG, const u16* __restrict__ Vt,
    const float* __restrict__ gnw, const float* __restrict__ gnb) {
    __shared__ __align__(16) u16 Qs[4][64][32];
    __shared__ __align__(16) u16 Ks[2][4][32][32];
    __shared__ __align__(16) u16 Vs[2][256][32];
    __shared__ u16 Ss[64][40];
    const int id = blockIdx.x;
    const int halfg = id >> 8, r5 = id & 255;
    const int bh = r5 >> 4, i16 = r5 & 15;
    const int tile = halfg ? i16 : 31 - i16;   // pair (i, i+256) work = 68 steps const
    const int b = bh >> 3, h = bh & 7;
    const int t = threadIdx.x;
    const int wave = t >> 6, lane = t & 63, quad = lane >> 4, l16 = lane & 15;
    const u32 lo = __builtin_amdgcn_readfirstlane((u32)(wave * 1024));
    const u16* Qbase = QKVG + (long)b * 2048 * 6144 + h * 128;
    const u16* Kbase = Qbase + 1024;
    const u16* Vbase = Vt + (long)(b * 8 + h) * 256 * 2048;
    u16* Gseg = QKVG + (long)b * 2048 * 6144 + 4096 + h * 256;
    // read-side slot XOR, pre-scaled to u16 units (slot index * 8)
    const int sq8 = (((l16 & 3) ^ ((l16 >> 2) & 3))) << 3;

    float g = 1.f - expf(-3.4657359027997265f + (-0.3960841031771116f) * (float)h);
    float log2g = log2f(g);
    const float gi16 = exp2f(log2g * -16.f);   // γ^-16
    const float gi32 = gi16 * gi16;            // γ^-32 (per-step update)
    const float gf[4] = {1.f, g, g*g, g*g*g};
    const int srow0 = tile*64 + wave*16 + quad*4;
    float drun = exp2f(log2g * (float)(srow0 - l16));   // γ^(srow0 - l16) at jt=0

    auto issueKV = [&](int jt, int buf) {
#pragma unroll
        for (int i = 0; i < 2; i++) {
            int c = t + i * 256;
            int ks = c >> 7, row = (c >> 2) & 31;
            int cbs = (c & 3) ^ ((c >> 2) & 3) ^ ((c >> 4) & 3);   // inverse-swz source
            async_ld16(Kbase + (long)(jt*32 + row) * 6144 + ks*32 + cbs*8,
                       (const char*)Ks + buf*8192 + i*4096 + lo);
        }
#pragma unroll
        for (int i = 0; i < 4; i++) {
            int c = t + i * 256;
            int row = c >> 2;
            int cbs = (c & 3) ^ ((c >> 2) & 3) ^ ((c >> 4) & 3);
            async_ld16(Vbase + (long)row * 2048 + jt*32 + cbs*8,
                       (const char*)Vs + buf*16384 + i*4096 + lo);
        }
    };

    // prologue: Q tile + (K,V) for jt=0 into buf 0
#pragma unroll
    for (int i = 0; i < 4; i++) {
        int c = t + i * 256;
        int ks = c >> 8, row = (c >> 2) & 63;
        int cbs = (c & 3) ^ ((c >> 2) & 3) ^ ((c >> 4) & 3);
        async_ld16(Qbase + (long)(tile*64 + row) * 6144 + ks*32 + cbs*8,
                   (const char*)Qs + i*4096 + lo);
    }
    issueKV(0, 0);

    float gw[16], gbv[16];
#pragma unroll
    for (int nt = 0; nt < 16; nt++) {
        gw[nt]  = gnw[h*256 + nt*16 + l16];
        gbv[nt] = gnb[h*256 + nt*16 + l16];
    }
    f32x4 oacc[16];
#pragma unroll
    for (int nt = 0; nt < 16; nt++) oacc[nt] = (f32x4){0.f, 0.f, 0.f, 0.f};
    __syncthreads();

    const int njt = 2 * tile + 2;
    for (int jt = 0; jt < njt; jt++) {
        const int cur = jt & 1;
        if (jt + 1 < njt) issueKV(jt + 1, cur ^ 1);   // prefetch overlaps compute
        // QK^T (swizzled fragment reads: 2-way banks instead of 8-way)
        f32x4 s0 = (f32x4){0.f,0.f,0.f,0.f}, s1 = (f32x4){0.f,0.f,0.f,0.f};
#pragma unroll
        for (int ks = 0; ks < 4; ks++) {
            short8 aq = *(const short8*)&Qs[ks][wave*16 + l16][(quad*8) ^ sq8];
            short8 b0 = *(const short8*)&Ks[cur][ks][l16][(quad*8) ^ sq8];
            short8 b1 = *(const short8*)&Ks[cur][ks][16 + l16][(quad*8) ^ sq8];
            s0 = __builtin_amdgcn_mfma_f32_16x16x32_bf16(aq, b0, s0, 0, 0, 0);
            s1 = __builtin_amdgcn_mfma_f32_16x16x32_bf16(aq, b1, s1, 0, 0, 0);
        }
        // decay + causal mask -> Ss (wave-private rows: no barrier needed)
#pragma unroll
        for (int reg = 0; reg < 4; reg++) {
            int srow = srow0 + reg;
            int tc0 = jt*32 + l16, tc1 = tc0 + 16;
            float dbase = drun * gf[reg];               // γ^(srow - tc0)
            float d0 = (srow >= tc0) ? dbase : 0.f;
            float d1 = (srow >= tc1) ? dbase * gi16 : 0.f;
            Ss[wave*16 + quad*4 + reg][l16]      = f2b(s0[reg] * d0);
            Ss[wave*16 + quad*4 + reg][16 + l16] = f2b(s1[reg] * d1);
        }
        drun *= gi32;
        // PV: O[64x256] += S[64x32] @ V[32x256]
        short8 as = *(const short8*)&Ss[wave*16 + l16][quad*8];
#pragma unroll
        for (int nt = 0; nt < 16; nt++) {
            short8 bv = *(const short8*)&Vs[cur][nt*16 + l16][(quad*8) ^ sq8];
            oacc[nt] = __builtin_amdgcn_mfma_f32_16x16x32_bf16(as, bv, oacc[nt], 0, 0, 0);
        }
        __syncthreads();   // drains prefetch + guards buf reuse
    }

    // fused groupnorm + silu(G) gate, written in-place over G segment
#pragma unroll
    for (int reg = 0; reg < 4; reg++) {
        float s = 0.f, q = 0.f;
#pragma unroll
        for (int nt = 0; nt < 16; nt++) { float v = oacc[nt][reg]; s += v; q += v*v; }
#pragma unroll
        for (int m = 1; m < 16; m <<= 1) { s += __shfl_xor(s, m, 16); q += __shfl_xor(q, m, 16); }
        float mean = s * (1.f/256.f);
        float var  = q * (1.f/256.f) - mean*mean;
        float rstd = rsqrtf(var + 1e-5f);
        int srow = srow0 + reg;
        u16* grow = Gseg + (long)srow * 6144;
#pragma unroll
        for (int nt = 0; nt < 16; nt++) {
            float gval = b2f(grow[nt*16 + l16]);
            float y = (oacc[nt][reg] - mean) * rstd * gw[nt] + gbv[nt];
            float sg = gval / (1.f + exp2f(-1.4426950408889634f * gval));
            grow[nt*16 + l16] = f2b(sg * y);
        }
    }
}

extern "C" void kernel_launch(void* const* d_in, const int* in_sizes, int n_in,
                              void* d_out, int out_size, void* d_ws, size_t ws_size,
                              hipStream_t stream) {
    (void)in_sizes; (void)n_in; (void)out_size; (void)ws_size;
    const float* X    = (const float*)d_in[0];
    const float* Wq   = (const float*)d_in[1];
    const float* Wk   = (const float*)d_in[2];
    const float* Wv   = (const float*)d_in[3];
    const float* WG   = (const float*)d_in[4];
    const float* WO   = (const float*)d_in[5];
    const float* gnw  = (const float*)d_in[6];
    const float* gnb  = (const float*)d_in[7];
    const float* ln1w = (const float*)d_in[8];
    const float* ln1b = (const float*)d_in[9];
    const float* ln2w = (const float*)d_in[10];
    const float* ln2b = (const float*)d_in[11];
    const float* fw1  = (const float*)d_in[12];
    const float* fb1  = (const float*)d_in[13];
    const float* fw2  = (const float*)d_in[14];
    const float* fb2  = (const float*)d_in[15];

    constexpr int D = 1024, FFN = 4096;
    constexpr int M = 4096; // B*S rows
    constexpr long MB = 1048576;

    char* ws = (char*)d_ws;
    // weights (persistent until consumed):
    u16* WT   = (u16*)(ws + 0*MB);    // QKVG combined (6144,1024)  12 MB [..QKVG gemm]
    u16* WOT  = (u16*)(ws + 12*MB);   // (1024, 2048)                4 MB [..WO]
    u16* fw1T = (u16*)(ws + 16*MB);   // (4096, 1024)                8 MB [..FFN1]
    u16* fw2T = (u16*)(ws + 24*MB);   // (1024, 4096)                8 MB [..FFN2]
    // activations:
    u16*   QKVG = (u16*)(ws + 32*MB); // bf16 (B,S,6144) 48 MB [QKVG gemm .. WO]
                                      //   V segment row-major unused (V goes straight to Vt);
                                      //   WO parks fp32 partials in Q/K/V seg bytes of each row
    u16*   Xn   = (u16*)(ws + 80*MB); // bf16 (B,S,D)     8 MB [prep .. QKVG gemm]
    float4* xtab= (float4*)(ws + 88*MB);// fp32 table     2 MB [prep .. QKVG gemm]
    u16*   Vt   = (u16*)(ws + 90*MB); // bf16 (B,H,256,S)16 MB [QKVG gemm .. retention]
    u16*   hb   = (u16*)(ws + 0*MB);  // bf16 (B,S,D)     8 MB [ln2_combine .. FFN1] (reuses WT)
    u16*   mid  = (u16*)(ws + 32*MB); // bf16 (B,S,FFN)  32 MB [FFN1 .. FFN2]        (reuses QKVG)

    // 1. fused prep: 7x weight transpose + xPos table + LN1
    prep_k<<<20992, 256, 0, stream>>>(Wq, Wk, Wv, WG, WO, fw1, fw2, X, ln1w, ln1b,
                                      WT, WOT, fw1T, fw2T, xtab, Xn);
    // 2. fused QKVG projection + xPos epilogue; V blocks stored transposed into Vt [BK=32]
    mgemm<EPI_QKVG, 1><<<1536, 256, 0, stream>>>(
        Xn, WT, QKVG, D, D, 6144, (const float*)xtab, Vt);
    // 3. retention + groupnorm + silu-gate -> in-place on G segment [LDS swizzled]
    retention_mfma<<<512, 256, 0, stream>>>(QKVG, Vt, gnw, gnb);
    // 4. WO split-K x2: partials into dead Q/K/V segment bytes of QKVG rows  [BK=64]
    mgemm_sk<0><<<512, 256, 0, stream>>>(
        QKVG + 4096, WOT, (float*)QKVG, 2048, 1024, 6144, 3072, 1024);
    // 5. combine + residual + LN2 -> d_out init (X2+fb2, fp32) and hb (bf16)
    ln2_combine<<<M, 256, 0, stream>>>((const float*)QKVG, X, ln2w, ln2b, fb2,
                                       (float*)d_out, hb);
    // 6. mid = gelu_fast(hb @ W1 + b1)  bf16  [BK=64]
    mgemm<EPI_GELU_BIAS, 2><<<1024, 256, 0, stream>>>(
        hb, fw1T, mid, D, D, FFN, fb1, nullptr);
    // 7. FFN2 split-K x2: atomicAdd both slices directly into pre-initialized d_out
    mgemm_sk<1><<<512, 256, 0, stream>>>(
        mid, fw2T, (float*)d_out, 4096, 2048, 4096, 1024, 0);
}

// Round 7
// 449.778 us; speedup vs baseline: 1.0054x; 1.0054x over previous
//
#include <hip/hip_runtime.h>
#include <hip/hip_bf16.h>

typedef unsigned short u16;
typedef unsigned int   u32;
typedef short short8 __attribute__((ext_vector_type(8)));
typedef float f32x4  __attribute__((ext_vector_type(4)));

// ---------- bf16 helpers ----------
__device__ __forceinline__ float b2f(u16 u) { return __uint_as_float(((u32)u) << 16); }
__device__ __forceinline__ u16 f2b(float f) {
    u32 u = __float_as_uint(f);
    u += 0x7FFF + ((u >> 16) & 1);   // RTNE
    return (u16)(u >> 16);
}
// fast gelu (tanh form), |err| < 4e-4 (far below bf16 storage rounding)
__device__ __forceinline__ float gelu_fast(float v) {
    float a = v * (2.302118f + 0.102953f * v * v);   // 2*log2e*0.79788456*(1+0.044715 v^2)
    a = fminf(a, 120.f);                              // avoid inf/inf for v > ~10.8
    float e = exp2f(a);
    return v * e / (1.f + e);
}

// ---------- async global->LDS 16B (wave-uniform LDS base + lane*16) ----------
typedef const unsigned int __attribute__((address_space(1)))* gas1;
typedef unsigned int __attribute__((address_space(3)))* las3;
__device__ __forceinline__ void async_ld16(const void* g, const void* l) {
    __builtin_amdgcn_global_load_lds((gas1)(unsigned long long)g,
                                     (las3)(unsigned int)(unsigned long long)l,
                                     16, 0, 0);
}

// ================= fused prep: 7x wtrans + xPos table + LN1 =================
__device__ __forceinline__ void wtrans_body(const float* __restrict__ W, u16* __restrict__ Wt,
                                            int K, int N, int bx, int by, int bz) {
    __shared__ u16 tile[32][36];
    const int k0 = bx * 32, n0 = by * 32;
    const float* Wz = W + (long)bz * K * N;
    u16* Wtz = Wt + (long)bz * K * N;
    const int t = threadIdx.x;
    const int r = t >> 3, c = (t & 7) * 4;
    float4 v = *(const float4*)(Wz + (long)(k0 + r) * N + n0 + c);
    tile[r][c+0] = f2b(v.x); tile[r][c+1] = f2b(v.y);
    tile[r][c+2] = f2b(v.z); tile[r][c+3] = f2b(v.w);
    __syncthreads();
    uint2 pk;
    pk.x = (u32)tile[c+0][r] | ((u32)tile[c+1][r] << 16);
    pk.y = (u32)tile[c+2][r] | ((u32)tile[c+3][r] << 16);
    *(uint2*)(Wtz + (long)(n0 + r) * K + k0 + c) = pk;
}

__device__ __forceinline__ void xtab_body(float4* __restrict__ tab, int blk) {
    int idx = blk * 256 + threadIdx.x;   // 0..131071
    int j = idx & 63, s = idx >> 6;
    float sv = (2.f * j + 51.2f) / 179.2f;
    float scale = exp2f(log2f(sv) * ((float)s * (1.f / 512.f)));
    float inv_freq = exp2f((float)j * (-13.287712379549449f / 64.f));
    float ang = (float)s * inv_freq;
    float sn = sinf(ang), cs = cosf(ang);
    tab[idx] = make_float4(cs * scale, sn * scale, cs / scale, sn / scale);
}

__device__ __forceinline__ void ln_body(const float* __restrict__ X,
                                        const float* __restrict__ w,
                                        const float* __restrict__ bb,
                                        u16* __restrict__ out, long row) {
    const int t = threadIdx.x;
    float4 p = ((const float4*)(X + row * 1024))[t];
    float x[4] = { p.x, p.y, p.z, p.w };
    float s = x[0]+x[1]+x[2]+x[3];
    float q = x[0]*x[0]+x[1]*x[1]+x[2]*x[2]+x[3]*x[3];
#pragma unroll
    for (int o = 32; o > 0; o >>= 1) { s += __shfl_down(s, o, 64); q += __shfl_down(q, o, 64); }
    __shared__ float aS[4], aQ[4];
    if ((t & 63) == 0) { aS[t >> 6] = s; aQ[t >> 6] = q; }
    __syncthreads();
    s = aS[0]+aS[1]+aS[2]+aS[3];
    q = aQ[0]+aQ[1]+aQ[2]+aQ[3];
    float mean = s * (1.f/1024.f);
    float var  = q * (1.f/1024.f) - mean*mean;
    float rstd = rsqrtf(var + 1e-5f);
    float4 wv = ((const float4*)w)[t];
    float4 bv = ((const float4*)bb)[t];
    uint2 r;
    r.x = (u32)f2b((x[0]-mean)*rstd*wv.x + bv.x) | ((u32)f2b((x[1]-mean)*rstd*wv.y + bv.y) << 16);
    r.y = (u32)f2b((x[2]-mean)*rstd*wv.z + bv.z) | ((u32)f2b((x[3]-mean)*rstd*wv.w + bv.w) << 16);
    ((uint2*)(out + row * 1024))[t] = r;
}

__global__ __launch_bounds__(256) void prep_k(
    const float* __restrict__ Wq, const float* __restrict__ Wk,
    const float* __restrict__ Wv, const float* __restrict__ WG,
    const float* __restrict__ WO, const float* __restrict__ fw1,
    const float* __restrict__ fw2, const float* __restrict__ X,
    const float* __restrict__ ln1w, const float* __restrict__ ln1b,
    u16* __restrict__ WT, u16* __restrict__ WOT,
    u16* __restrict__ fw1T, u16* __restrict__ fw2T,
    float4* __restrict__ xtab, u16* __restrict__ Xn) {
    const int id = blockIdx.x;
    if (id < 16384) {
        const float* W; u16* Wt; int K, N, bx, by, bz = 0;
        if (id < 1024)       { W=Wq;  Wt=WT;           K=1024; N=128;  int l=id;       bx=l&31;  by=(l>>5)&3; bz=l>>7; }
        else if (id < 2048)  { W=Wk;  Wt=WT+1048576;   K=1024; N=128;  int l=id-1024;  bx=l&31;  by=(l>>5)&3; bz=l>>7; }
        else if (id < 4096)  { W=Wv;  Wt=WT+2097152;   K=1024; N=256;  int l=id-2048;  bx=l&31;  by=(l>>5)&7; bz=l>>8; }
        else if (id < 6144)  { W=WG;  Wt=WT+4194304;   K=1024; N=2048; int l=id-4096;  bx=l&31;  by=l>>5; }
        else if (id < 8192)  { W=WO;  Wt=WOT;          K=2048; N=1024; int l=id-6144;  bx=l&63;  by=l>>6; }
        else if (id < 12288) { W=fw1; Wt=fw1T;         K=1024; N=4096; int l=id-8192;  bx=l&31;  by=l>>5; }
        else                 { W=fw2; Wt=fw2T;         K=4096; N=1024; int l=id-12288; bx=l&127; by=l>>7; }
        wtrans_body(W, Wt, K, N, bx, by, bz);
    } else if (id < 16896) {
        xtab_body(xtab, id - 16384);
    } else {
        ln_body(X, ln1w, ln1b, Xn, id - 16896);
    }
}

// ---------- combine WO partials + residual X, then LN2 -> X2 (fp32) and hb (bf16) ----------
__global__ __launch_bounds__(256) void ln2_combine(const float* __restrict__ P,
                                                   const float* __restrict__ X,
                                                   const float* __restrict__ w,
                                                   const float* __restrict__ bb,
                                                   float* __restrict__ X2,
                                                   u16* __restrict__ hb) {
    const long row = blockIdx.x;
    const int t = threadIdx.x;
    const float* p = P + row * 3072;
    float4 a = ((const float4*)p)[t];
    float4 c = ((const float4*)(p + 1024))[t];
    float4 xr = ((const float4*)(X + row * 1024))[t];
    float x[4] = { a.x+c.x+xr.x, a.y+c.y+xr.y, a.z+c.z+xr.z, a.w+c.w+xr.w };
    ((float4*)(X2 + row * 1024))[t] = make_float4(x[0], x[1], x[2], x[3]);
    float s = x[0]+x[1]+x[2]+x[3];
    float q = x[0]*x[0]+x[1]*x[1]+x[2]*x[2]+x[3]*x[3];
#pragma unroll
    for (int o = 32; o > 0; o >>= 1) { s += __shfl_down(s, o, 64); q += __shfl_down(q, o, 64); }
    __shared__ float aS[4], aQ[4];
    if ((t & 63) == 0) { aS[t >> 6] = s; aQ[t >> 6] = q; }
    __syncthreads();
    s = aS[0]+aS[1]+aS[2]+aS[3];
    q = aQ[0]+aQ[1]+aQ[2]+aQ[3];
    float mean = s * (1.f/1024.f);
    float var  = q * (1.f/1024.f) - mean*mean;
    float rstd = rsqrtf(var + 1e-5f);
    float4 wv = ((const float4*)w)[t];
    float4 bv = ((const float4*)bb)[t];
    uint2 r;
    r.x = (u32)f2b((x[0]-mean)*rstd*wv.x + bv.x) | ((u32)f2b((x[1]-mean)*rstd*wv.y + bv.y) << 16);
    r.y = (u32)f2b((x[2]-mean)*rstd*wv.z + bv.z) | ((u32)f2b((x[3]-mean)*rstd*wv.w + bv.w) << 16);
    ((uint2*)(hb + row * 1024))[t] = r;
}

// ---------- combine FFN2 partials + bias + X2 -> d_out (fp32) ----------
__global__ __launch_bounds__(256) void ffn2_combine(const float* __restrict__ P,
                                                    const float* __restrict__ b2,
                                                    const float* __restrict__ X2,
                                                    float* __restrict__ out) {
    const long row = blockIdx.x;
    const int t = threadIdx.x;
    float4 p0 = ((const float4*)(P + row * 1024))[t];
    float4 p1 = ((const float4*)(P + 16777216 + row * 1024))[t];
    float4 x2 = ((const float4*)(X2 + row * 1024))[t];
    float4 bv = ((const float4*)b2)[t];
    ((float4*)(out + row * 1024))[t] = make_float4(
        p0.x + p1.x + x2.x + bv.x, p0.y + p1.y + x2.y + bv.y,
        p0.z + p1.z + x2.z + bv.z, p0.w + p1.w + x2.w + bv.w);
}

// ---------- MFMA GEMM, templated panel count (BK = PANELS*32) ----------
// C = A[M][K] @ Bt[N][K]^T, bf16->fp32->bf16. mb innermost (mb = pid & 31), M=4096.
// EPI_QKVG: rotary for c<2048 (via xtab in `bias`); V-range blocks (2048<=col0<4096)
// store DIRECTLY TRANSPOSED into Vt (B,H,256,S) and skip the row-major write.
// T2/T21 swizzle: 64-B LDS rows (4x16B slots) give 8-way bank conflicts on the
// fragment ds_read_b128 (bank group = 16*(row&1)+slot*4; 8 of 16 lanes per group).
// Fix: read slot' = quad ^ ((l16>>1)&3) -> 2 lanes/group (free); staged content
// pre-permuted via global slot (t&3) ^ ((t>>3)&3)  (LDS row = t>>2, so key =
// (row>>1)&3 on both sides; fragment rows = 16k + l16 -> key = (l16>>1)&3).
enum { EPI_GELU_BIAS = 2, EPI_QKVG = 4 };

template<int EPI, int PANELS>
__global__ __launch_bounds__(256) void mgemm(
    const u16* __restrict__ A, const u16* __restrict__ Bt, u16* __restrict__ Cv,
    int K, int aStride, long cStride,
    const float* __restrict__ bias, u16* __restrict__ Vt) {
    __shared__ __align__(16) u16 As[PANELS * 4096];
    __shared__ __align__(16) u16 Bs[PANELS * 4096];
    const int pid = blockIdx.x;
    const int mb = pid & 31;
    const int nb = pid >> 5;
    const int t = threadIdx.x;
    const int row0 = mb * 128, col0 = nb * 128;
    const int wave = t >> 6, lane = t & 63;
    const int wm = wave >> 1, wn = wave & 1;
    const int quad = lane >> 4, l16 = lane & 15;
    const int sgc = ((t & 3) ^ ((t >> 3) & 3)) * 8;     // stage-side swizzled column
    const u16* Ag = A + (long)(row0 + (t >> 2)) * aStride + sgc;
    const u16* Bg = Bt + (long)(col0 + (t >> 2)) * K + sgc;
    const long aj = (long)64 * aStride;
    const long bj = (long)64 * K;
    const u32 lo = __builtin_amdgcn_readfirstlane((u32)(wave * 1024));
    const int swr = ((l16 >> 1) & 3) << 3;              // read-side slot XOR (u16 units)

    f32x4 acc[4][4];
#pragma unroll
    for (int i = 0; i < 4; i++)
#pragma unroll
        for (int j = 0; j < 4; j++) acc[i][j] = (f32x4){0.f, 0.f, 0.f, 0.f};

    for (int k0 = 0; k0 < K; k0 += PANELS * 32) {
#pragma unroll
        for (int h = 0; h < PANELS; h++) {
            const u16* Agh = Ag + k0 + h * 32;
            const u16* Bgh = Bg + k0 + h * 32;
            async_ld16(Agh,      (const char*)As + h*8192 + lo);
            async_ld16(Agh + aj, (const char*)As + h*8192 + 4096 + lo);
            async_ld16(Bgh,      (const char*)Bs + h*8192 + lo);
            async_ld16(Bgh + bj, (const char*)Bs + h*8192 + 4096 + lo);
        }
        __syncthreads();
#pragma unroll
        for (int h = 0; h < PANELS; h++) {
            short8 af[4], bf[4];
#pragma unroll
            for (int mt = 0; mt < 4; mt++)
                af[mt] = *(const short8*)(As + h*4096 + (wm*64 + mt*16 + l16) * 32 + ((quad*8) ^ swr));
#pragma unroll
            for (int nt = 0; nt < 4; nt++)
                bf[nt] = *(const short8*)(Bs + h*4096 + (wn*64 + nt*16 + l16) * 32 + ((quad*8) ^ swr));
#pragma unroll
            for (int mt = 0; mt < 4; mt++)
#pragma unroll
                for (int nt = 0; nt < 4; nt++)
                    acc[mt][nt] = __builtin_amdgcn_mfma_f32_16x16x32_bf16(af[mt], bf[nt], acc[mt][nt], 0, 0, 0);
        }
        __syncthreads();
    }

    if constexpr (EPI == EPI_QKVG) {
        if (col0 >= 2048 && col0 < 4096) {
            // V blocks: store transposed into Vt (B,H,256,S). reg 0..3 = 4 consecutive s.
            const int bq = row0 >> 11;
            const int sb = (row0 & 2047) + wm*64 + quad*4;
#pragma unroll
            for (int mt = 0; mt < 4; mt++) {
#pragma unroll
                for (int nt = 0; nt < 4; nt++) {
                    int vc = (col0 - 2048) + wn*64 + nt*16 + l16;
                    u16* dst = Vt + ((long)((bq << 3) + (vc >> 8)) * 256 + (vc & 255)) * 2048
                                  + sb + mt*16;
                    uint2 pk;
                    pk.x = (u32)f2b(acc[mt][nt][0]) | ((u32)f2b(acc[mt][nt][1]) << 16);
                    pk.y = (u32)f2b(acc[mt][nt][2]) | ((u32)f2b(acc[mt][nt][3]) << 16);
                    *(uint2*)dst = pk;
                }
            }
            return;
        }
    }

#pragma unroll
    for (int mt = 0; mt < 4; mt++) {
#pragma unroll
        for (int reg = 0; reg < 4; reg++) {
            int r = row0 + wm*64 + mt*16 + quad*4 + reg;
#pragma unroll
            for (int nt = 0; nt < 4; nt++) {
                int c = col0 + wn*64 + nt*16 + l16;
                float v = acc[mt][nt][reg];
                if constexpr (EPI == EPI_GELU_BIAS) {
                    v = gelu_fast(v + bias[c]);
                } else if constexpr (EPI == EPI_QKVG) {
                    if (c < 2048) {  // xPos rotary: Q (c<1024, up) / K (else, down) via table
                        int j = (c & 127) >> 1;
                        float4 tb = ((const float4*)bias)[((r & 2047) << 6) + j];
                        float cs = (c < 1024) ? tb.x : tb.z;
                        float sn = (c < 1024) ? tb.y : tb.w;
                        float partner = __shfl_xor(v, 1, 64);
                        v = v * cs + ((c & 1) ? partner : -partner) * sn;
                    }
                }
                Cv[(long)r * cStride + c] = f2b(v);
            }
        }
    }
}

// ---------- split-K (x2) MFMA GEMM, BK=64 paneled, N=1024, fp32 partial out ----------
// Same T21 swizzle as mgemm (identical LDS geometry).
__global__ __launch_bounds__(256) void mgemm_sk(
    const u16* __restrict__ A, const u16* __restrict__ Bt, float* __restrict__ P,
    int K, int kHalf, int aStride, long pRowStride, long sliceOff) {
    __shared__ __align__(16) u16 As[2 * 4096];
    __shared__ __align__(16) u16 Bs[2 * 4096];
    const int pid = blockIdx.x;
    const int mb = pid & 31;
    const int nb = (pid & 255) >> 5;
    const int slice = pid >> 8;
    const int t = threadIdx.x;
    const int row0 = mb * 128, col0 = nb * 128;
    const int wave = t >> 6, lane = t & 63;
    const int wm = wave >> 1, wn = wave & 1;
    const int quad = lane >> 4, l16 = lane & 15;
    const int sgc = ((t & 3) ^ ((t >> 3) & 3)) * 8;     // stage-side swizzled column
    const u16* Ag = A + (long)(row0 + (t >> 2)) * aStride + sgc;
    const u16* Bg = Bt + (long)(col0 + (t >> 2)) * K + sgc;
    const long aj = (long)64 * aStride;
    const long bj = (long)64 * K;
    const u32 lo = __builtin_amdgcn_readfirstlane((u32)(wave * 1024));
    const int swr = ((l16 >> 1) & 3) << 3;              // read-side slot XOR (u16 units)

    f32x4 acc[4][4];
#pragma unroll
    for (int i = 0; i < 4; i++)
#pragma unroll
        for (int j = 0; j < 4; j++) acc[i][j] = (f32x4){0.f, 0.f, 0.f, 0.f};

    const int kBeg = slice * kHalf, kEnd = kBeg + kHalf;
    for (int k0 = kBeg; k0 < kEnd; k0 += 64) {
#pragma unroll
        for (int h = 0; h < 2; h++) {
            const u16* Agh = Ag + k0 + h * 32;
            const u16* Bgh = Bg + k0 + h * 32;
            async_ld16(Agh,      (const char*)As + h*8192 + lo);
            async_ld16(Agh + aj, (const char*)As + h*8192 + 4096 + lo);
            async_ld16(Bgh,      (const char*)Bs + h*8192 + lo);
            async_ld16(Bgh + bj, (const char*)Bs + h*8192 + 4096 + lo);
        }
        __syncthreads();
#pragma unroll
        for (int h = 0; h < 2; h++) {
            short8 af[4], bf[4];
#pragma unroll
            for (int mt = 0; mt < 4; mt++)
                af[mt] = *(const short8*)(As + h*4096 + (wm*64 + mt*16 + l16) * 32 + ((quad*8) ^ swr));
#pragma unroll
            for (int nt = 0; nt < 4; nt++)
                bf[nt] = *(const short8*)(Bs + h*4096 + (wn*64 + nt*16 + l16) * 32 + ((quad*8) ^ swr));
#pragma unroll
            for (int mt = 0; mt < 4; mt++)
#pragma unroll
                for (int nt = 0; nt < 4; nt++)
                    acc[mt][nt] = __builtin_amdgcn_mfma_f32_16x16x32_bf16(af[mt], bf[nt], acc[mt][nt], 0, 0, 0);
        }
        __syncthreads();
    }

    float* Pb = P + slice * sliceOff;
#pragma unroll
    for (int mt = 0; mt < 4; mt++) {
#pragma unroll
        for (int reg = 0; reg < 4; reg++) {
            int r = row0 + wm*64 + mt*16 + quad*4 + reg;
#pragma unroll
            for (int nt = 0; nt < 4; nt++) {
                int c = col0 + wn*64 + nt*16 + l16;
                Pb[(long)r * pRowStride + c] = acc[mt][nt][reg];
            }
        }
    }
}

// ---------- MFMA retention + fused groupnorm + fused silu-gate ----------
// grid 512 (1D). QKVG (B,S,6144): Q cols 0..1023, K 1024..2047, G 4096..6143.
// Writes gated = silu(G)*groupnorm(O) in-place over the G segment. Vt (B,H,256,S).
// T2/T21 swizzle on Qs/Ks/Vs (see R5 notes): read slot = quad ^ (l16&3) ^ ((l16>>2)&3),
// staged via global source column cb ^ ((c>>2)&3) ^ ((c>>4)&3).
__global__ __launch_bounds__(256) void retention_mfma(
    u16* __restrict__ QKVG, const u16* __restrict__ Vt,
    const float* __restrict__ gnw, const float* __restrict__ gnb) {
    __shared__ __align__(16) u16 Qs[4][64][32];
    __shared__ __align__(16) u16 Ks[2][4][32][32];
    __shared__ __align__(16) u16 Vs[2][256][32];
    __shared__ u16 Ss[64][40];
    const int id = blockIdx.x;
    const int halfg = id >> 8, r5 = id & 255;
    const int bh = r5 >> 4, i16 = r5 & 15;
    const int tile = halfg ? i16 : 31 - i16;   // pair (i, i+256) work = 68 steps const
    const int b = bh >> 3, h = bh & 7;
    const int t = threadIdx.x;
    const int wave = t >> 6, lane = t & 63, quad = lane >> 4, l16 = lane & 15;
    const u32 lo = __builtin_amdgcn_readfirstlane((u32)(wave * 1024));
    const u16* Qbase = QKVG + (long)b * 2048 * 6144 + h * 128;
    const u16* Kbase = Qbase + 1024;
    const u16* Vbase = Vt + (long)(b * 8 + h) * 256 * 2048;
    u16* Gseg = QKVG + (long)b * 2048 * 6144 + 4096 + h * 256;
    // read-side slot XOR, pre-scaled to u16 units (slot index * 8)
    const int sq8 = (((l16 & 3) ^ ((l16 >> 2) & 3))) << 3;

    float g = 1.f - expf(-3.4657359027997265f + (-0.3960841031771116f) * (float)h);
    float log2g = log2f(g);
    const float gi16 = exp2f(log2g * -16.f);   // γ^-16
    const float gi32 = gi16 * gi16;            // γ^-32 (per-step update)
    const float gf[4] = {1.f, g, g*g, g*g*g};
    const int srow0 = tile*64 + wave*16 + quad*4;
    float drun = exp2f(log2g * (float)(srow0 - l16));   // γ^(srow0 - l16) at jt=0

    auto issueKV = [&](int jt, int buf) {
#pragma unroll
        for (int i = 0; i < 2; i++) {
            int c = t + i * 256;
            int ks = c >> 7, row = (c >> 2) & 31;
            int cbs = (c & 3) ^ ((c >> 2) & 3) ^ ((c >> 4) & 3);   // inverse-swz source
            async_ld16(Kbase + (long)(jt*32 + row) * 6144 + ks*32 + cbs*8,
                       (const char*)Ks + buf*8192 + i*4096 + lo);
        }
#pragma unroll
        for (int i = 0; i < 4; i++) {
            int c = t + i * 256;
            int row = c >> 2;
            int cbs = (c & 3) ^ ((c >> 2) & 3) ^ ((c >> 4) & 3);
            async_ld16(Vbase + (long)row * 2048 + jt*32 + cbs*8,
                       (const char*)Vs + buf*16384 + i*4096 + lo);
        }
    };

    // prologue: Q tile + (K,V) for jt=0 into buf 0
#pragma unroll
    for (int i = 0; i < 4; i++) {
        int c = t + i * 256;
        int ks = c >> 8, row = (c >> 2) & 63;
        int cbs = (c & 3) ^ ((c >> 2) & 3) ^ ((c >> 4) & 3);
        async_ld16(Qbase + (long)(tile*64 + row) * 6144 + ks*32 + cbs*8,
                   (const char*)Qs + i*4096 + lo);
    }
    issueKV(0, 0);

    float gw[16], gbv[16];
#pragma unroll
    for (int nt = 0; nt < 16; nt++) {
        gw[nt]  = gnw[h*256 + nt*16 + l16];
        gbv[nt] = gnb[h*256 + nt*16 + l16];
    }
    f32x4 oacc[16];
#pragma unroll
    for (int nt = 0; nt < 16; nt++) oacc[nt] = (f32x4){0.f, 0.f, 0.f, 0.f};
    __syncthreads();

    const int njt = 2 * tile + 2;
    for (int jt = 0; jt < njt; jt++) {
        const int cur = jt & 1;
        if (jt + 1 < njt) issueKV(jt + 1, cur ^ 1);   // prefetch overlaps compute
        // QK^T (swizzled fragment reads: 2-way banks instead of 8-way)
        f32x4 s0 = (f32x4){0.f,0.f,0.f,0.f}, s1 = (f32x4){0.f,0.f,0.f,0.f};
#pragma unroll
        for (int ks = 0; ks < 4; ks++) {
            short8 aq = *(const short8*)&Qs[ks][wave*16 + l16][(quad*8) ^ sq8];
            short8 b0 = *(const short8*)&Ks[cur][ks][l16][(quad*8) ^ sq8];
            short8 b1 = *(const short8*)&Ks[cur][ks][16 + l16][(quad*8) ^ sq8];
            s0 = __builtin_amdgcn_mfma_f32_16x16x32_bf16(aq, b0, s0, 0, 0, 0);
            s1 = __builtin_amdgcn_mfma_f32_16x16x32_bf16(aq, b1, s1, 0, 0, 0);
        }
        // decay + causal mask -> Ss (wave-private rows: no barrier needed)
#pragma unroll
        for (int reg = 0; reg < 4; reg++) {
            int srow = srow0 + reg;
            int tc0 = jt*32 + l16, tc1 = tc0 + 16;
            float dbase = drun * gf[reg];               // γ^(srow - tc0)
            float d0 = (srow >= tc0) ? dbase : 0.f;
            float d1 = (srow >= tc1) ? dbase * gi16 : 0.f;
            Ss[wave*16 + quad*4 + reg][l16]      = f2b(s0[reg] * d0);
            Ss[wave*16 + quad*4 + reg][16 + l16] = f2b(s1[reg] * d1);
        }
        drun *= gi32;
        // PV: O[64x256] += S[64x32] @ V[32x256]
        short8 as = *(const short8*)&Ss[wave*16 + l16][quad*8];
#pragma unroll
        for (int nt = 0; nt < 16; nt++) {
            short8 bv = *(const short8*)&Vs[cur][nt*16 + l16][(quad*8) ^ sq8];
            oacc[nt] = __builtin_amdgcn_mfma_f32_16x16x32_bf16(as, bv, oacc[nt], 0, 0, 0);
        }
        __syncthreads();   // drains prefetch + guards buf reuse
    }

    // fused groupnorm + silu(G) gate, written in-place over G segment
#pragma unroll
    for (int reg = 0; reg < 4; reg++) {
        float s = 0.f, q = 0.f;
#pragma unroll
        for (int nt = 0; nt < 16; nt++) { float v = oacc[nt][reg]; s += v; q += v*v; }
#pragma unroll
        for (int m = 1; m < 16; m <<= 1) { s += __shfl_xor(s, m, 16); q += __shfl_xor(q, m, 16); }
        float mean = s * (1.f/256.f);
        float var  = q * (1.f/256.f) - mean*mean;
        float rstd = rsqrtf(var + 1e-5f);
        int srow = srow0 + reg;
        u16* grow = Gseg + (long)srow * 6144;
#pragma unroll
        for (int nt = 0; nt < 16; nt++) {
            float gval = b2f(grow[nt*16 + l16]);
            float y = (oacc[nt][reg] - mean) * rstd * gw[nt] + gbv[nt];
            float sg = gval / (1.f + exp2f(-1.4426950408889634f * gval));
            grow[nt*16 + l16] = f2b(sg * y);
        }
    }
}

extern "C" void kernel_launch(void* const* d_in, const int* in_sizes, int n_in,
                              void* d_out, int out_size, void* d_ws, size_t ws_size,
                              hipStream_t stream) {
    (void)in_sizes; (void)n_in; (void)out_size; (void)ws_size;
    const float* X    = (const float*)d_in[0];
    const float* Wq   = (const float*)d_in[1];
    const float* Wk   = (const float*)d_in[2];
    const float* Wv   = (const float*)d_in[3];
    const float* WG   = (const float*)d_in[4];
    const float* WO   = (const float*)d_in[5];
    const float* gnw  = (const float*)d_in[6];
    const float* gnb  = (const float*)d_in[7];
    const float* ln1w = (const float*)d_in[8];
    const float* ln1b = (const float*)d_in[9];
    const float* ln2w = (const float*)d_in[10];
    const float* ln2b = (const float*)d_in[11];
    const float* fw1  = (const float*)d_in[12];
    const float* fb1  = (const float*)d_in[13];
    const float* fw2  = (const float*)d_in[14];
    const float* fb2  = (const float*)d_in[15];

    constexpr int D = 1024, FFN = 4096;
    constexpr int M = 4096; // B*S rows
    constexpr long MB = 1048576;

    char* ws = (char*)d_ws;
    // weights (persistent until consumed):
    u16* WT   = (u16*)(ws + 0*MB);    // QKVG combined (6144,1024)  12 MB [..QKVG gemm]
    u16* WOT  = (u16*)(ws + 12*MB);   // (1024, 2048)                4 MB [..WO]
    u16* fw1T = (u16*)(ws + 16*MB);   // (4096, 1024)                8 MB [..FFN1]
    u16* fw2T = (u16*)(ws + 24*MB);   // (1024, 4096)                8 MB [..FFN2]
    // activations:
    u16*   QKVG = (u16*)(ws + 32*MB); // bf16 (B,S,6144) 48 MB [QKVG gemm .. WO]
                                      //   V segment row-major unused (V goes straight to Vt);
                                      //   WO parks fp32 partials in Q/K/V seg bytes of each row
    u16*   Xn   = (u16*)(ws + 80*MB); // bf16 (B,S,D)     8 MB [prep .. QKVG gemm]
    float4* xtab= (float4*)(ws + 88*MB);// fp32 table     2 MB [prep .. QKVG gemm]
    u16*   Vt   = (u16*)(ws + 90*MB); // bf16 (B,H,256,S)16 MB [QKVG gemm .. retention]
    float* X2   = (float*)(ws + 80*MB);//fp32 (B,S,D)    16 MB [ln2_combine .. ffn2_combine] (reuses Xn+xtab+Vt head)
    u16*   hb   = (u16*)(ws + 0*MB);  // bf16 (B,S,D)     8 MB [ln2_combine .. FFN1] (reuses WT)
    u16*   mid  = (u16*)(ws + 32*MB); // bf16 (B,S,FFN)  32 MB [FFN1 .. FFN2]        (reuses QKVG)
    float* PF   = (float*)(ws + 0*MB);// FFN2 partials: P0 [0,16), P1 [64,80) MB

    // 1. fused prep: 7x weight transpose + xPos table + LN1
    prep_k<<<20992, 256, 0, stream>>>(Wq, Wk, Wv, WG, WO, fw1, fw2, X, ln1w, ln1b,
                                      WT, WOT, fw1T, fw2T, xtab, Xn);
    // 2. fused QKVG projection + xPos epilogue; V blocks stored transposed into Vt [BK=32]
    mgemm<EPI_QKVG, 1><<<1536, 256, 0, stream>>>(
        Xn, WT, QKVG, D, D, 6144, (const float*)xtab, Vt);
    // 3. retention + groupnorm + silu-gate -> in-place on G segment [LDS swizzled]
    retention_mfma<<<512, 256, 0, stream>>>(QKVG, Vt, gnw, gnb);
    // 4. WO split-K x2: partials into dead Q/K/V segment bytes of QKVG rows  [BK=64]
    mgemm_sk<<<512, 256, 0, stream>>>(
        QKVG + 4096, WOT, (float*)QKVG, 2048, 1024, 6144, 3072, 1024);
    // 5. combine + residual + LN2 -> X2 (fp32) and hb (bf16)
    ln2_combine<<<M, 256, 0, stream>>>((const float*)QKVG, X, ln2w, ln2b, X2, hb);
    // 6. mid = gelu_fast(hb @ W1 + b1)  bf16  [BK=64]
    mgemm<EPI_GELU_BIAS, 2><<<1024, 256, 0, stream>>>(
        hb, fw1T, mid, D, D, FFN, fb1, nullptr);
    // 7. FFN2 split-K x2: partials P0 [0,16), P1 [64,80) MB  [BK=64]
    mgemm_sk<<<512, 256, 0, stream>>>(
        mid, fw2T, PF, 4096, 2048, 4096, 1024, 16777216);
    // 8. combine + bias + X2 residual -> d_out (fp32)
    ffn2_combine<<<M, 256, 0, stream>>>(PF, fb2, X2, (float*)d_out);
}

// Round 8
// 432.813 us; speedup vs baseline: 1.0449x; 1.0392x over previous
//
#include <hip/hip_runtime.h>
#include <hip/hip_bf16.h>

typedef unsigned short u16;
typedef unsigned int   u32;
typedef short short8 __attribute__((ext_vector_type(8)));
typedef float f32x4  __attribute__((ext_vector_type(4)));

// ---------- bf16 helpers ----------
__device__ __forceinline__ float b2f(u16 u) { return __uint_as_float(((u32)u) << 16); }
__device__ __forceinline__ u16 f2b(float f) {
    u32 u = __float_as_uint(f);
    u += 0x7FFF + ((u >> 16) & 1);   // RTNE
    return (u16)(u >> 16);
}
// fast gelu (tanh form), |err| < 4e-4 (far below bf16 storage rounding)
__device__ __forceinline__ float gelu_fast(float v) {
    float a = v * (2.302118f + 0.102953f * v * v);   // 2*log2e*0.79788456*(1+0.044715 v^2)
    a = fminf(a, 120.f);                              // avoid inf/inf for v > ~10.8
    float e = exp2f(a);
    return v * e / (1.f + e);
}

// ---------- async global->LDS 16B (wave-uniform LDS base + lane*16) ----------
typedef const unsigned int __attribute__((address_space(1)))* gas1;
typedef unsigned int __attribute__((address_space(3)))* las3;
__device__ __forceinline__ void async_ld16(const void* g, const void* l) {
    __builtin_amdgcn_global_load_lds((gas1)(unsigned long long)g,
                                     (las3)(unsigned int)(unsigned long long)l,
                                     16, 0, 0);
}

// ================= fused prep: 7x wtrans + xPos table + LN1 =================
__device__ __forceinline__ void wtrans_body(const float* __restrict__ W, u16* __restrict__ Wt,
                                            int K, int N, int bx, int by, int bz) {
    __shared__ u16 tile[32][36];
    const int k0 = bx * 32, n0 = by * 32;
    const float* Wz = W + (long)bz * K * N;
    u16* Wtz = Wt + (long)bz * K * N;
    const int t = threadIdx.x;
    const int r = t >> 3, c = (t & 7) * 4;
    float4 v = *(const float4*)(Wz + (long)(k0 + r) * N + n0 + c);
    tile[r][c+0] = f2b(v.x); tile[r][c+1] = f2b(v.y);
    tile[r][c+2] = f2b(v.z); tile[r][c+3] = f2b(v.w);
    __syncthreads();
    uint2 pk;
    pk.x = (u32)tile[c+0][r] | ((u32)tile[c+1][r] << 16);
    pk.y = (u32)tile[c+2][r] | ((u32)tile[c+3][r] << 16);
    *(uint2*)(Wtz + (long)(n0 + r) * K + k0 + c) = pk;
}

__device__ __forceinline__ void xtab_body(float4* __restrict__ tab, int blk) {
    int idx = blk * 256 + threadIdx.x;   // 0..131071
    int j = idx & 63, s = idx >> 6;
    float sv = (2.f * j + 51.2f) / 179.2f;
    float scale = exp2f(log2f(sv) * ((float)s * (1.f / 512.f)));
    float inv_freq = exp2f((float)j * (-13.287712379549449f / 64.f));
    float ang = (float)s * inv_freq;
    float sn = sinf(ang), cs = cosf(ang);
    tab[idx] = make_float4(cs * scale, sn * scale, cs / scale, sn / scale);
}

__device__ __forceinline__ void ln_body(const float* __restrict__ X,
                                        const float* __restrict__ w,
                                        const float* __restrict__ bb,
                                        u16* __restrict__ out, long row) {
    const int t = threadIdx.x;
    float4 p = ((const float4*)(X + row * 1024))[t];
    float x[4] = { p.x, p.y, p.z, p.w };
    float s = x[0]+x[1]+x[2]+x[3];
    float q = x[0]*x[0]+x[1]*x[1]+x[2]*x[2]+x[3]*x[3];
#pragma unroll
    for (int o = 32; o > 0; o >>= 1) { s += __shfl_down(s, o, 64); q += __shfl_down(q, o, 64); }
    __shared__ float aS[4], aQ[4];
    if ((t & 63) == 0) { aS[t >> 6] = s; aQ[t >> 6] = q; }
    __syncthreads();
    s = aS[0]+aS[1]+aS[2]+aS[3];
    q = aQ[0]+aQ[1]+aQ[2]+aQ[3];
    float mean = s * (1.f/1024.f);
    float var  = q * (1.f/1024.f) - mean*mean;
    float rstd = rsqrtf(var + 1e-5f);
    float4 wv = ((const float4*)w)[t];
    float4 bv = ((const float4*)bb)[t];
    uint2 r;
    r.x = (u32)f2b((x[0]-mean)*rstd*wv.x + bv.x) | ((u32)f2b((x[1]-mean)*rstd*wv.y + bv.y) << 16);
    r.y = (u32)f2b((x[2]-mean)*rstd*wv.z + bv.z) | ((u32)f2b((x[3]-mean)*rstd*wv.w + bv.w) << 16);
    ((uint2*)(out + row * 1024))[t] = r;
}

__global__ __launch_bounds__(256) void prep_k(
    const float* __restrict__ Wq, const float* __restrict__ Wk,
    const float* __restrict__ Wv, const float* __restrict__ WG,
    const float* __restrict__ WO, const float* __restrict__ fw1,
    const float* __restrict__ fw2, const float* __restrict__ X,
    const float* __restrict__ ln1w, const float* __restrict__ ln1b,
    u16* __restrict__ WT, u16* __restrict__ WOT,
    u16* __restrict__ fw1T, u16* __restrict__ fw2T,
    float4* __restrict__ xtab, u16* __restrict__ Xn) {
    const int id = blockIdx.x;
    if (id < 16384) {
        const float* W; u16* Wt; int K, N, bx, by, bz = 0;
        if (id < 1024)       { W=Wq;  Wt=WT;           K=1024; N=128;  int l=id;       bx=l&31;  by=(l>>5)&3; bz=l>>7; }
        else if (id < 2048)  { W=Wk;  Wt=WT+1048576;   K=1024; N=128;  int l=id-1024;  bx=l&31;  by=(l>>5)&3; bz=l>>7; }
        else if (id < 4096)  { W=Wv;  Wt=WT+2097152;   K=1024; N=256;  int l=id-2048;  bx=l&31;  by=(l>>5)&7; bz=l>>8; }
        else if (id < 6144)  { W=WG;  Wt=WT+4194304;   K=1024; N=2048; int l=id-4096;  bx=l&31;  by=l>>5; }
        else if (id < 8192)  { W=WO;  Wt=WOT;          K=2048; N=1024; int l=id-6144;  bx=l&63;  by=l>>6; }
        else if (id < 12288) { W=fw1; Wt=fw1T;         K=1024; N=4096; int l=id-8192;  bx=l&31;  by=l>>5; }
        else                 { W=fw2; Wt=fw2T;         K=4096; N=1024; int l=id-12288; bx=l&127; by=l>>7; }
        wtrans_body(W, Wt, K, N, bx, by, bz);
    } else if (id < 16896) {
        xtab_body(xtab, id - 16384);
    } else {
        ln_body(X, ln1w, ln1b, Xn, id - 16896);
    }
}

// ---------- combine WO partials + residual X, then LN2 -> X2 (fp32) and hb (bf16) ----------
__global__ __launch_bounds__(256) void ln2_combine(const float* __restrict__ P,
                                                   const float* __restrict__ X,
                                                   const float* __restrict__ w,
                                                   const float* __restrict__ bb,
                                                   float* __restrict__ X2,
                                                   u16* __restrict__ hb) {
    const long row = blockIdx.x;
    const int t = threadIdx.x;
    const float* p = P + row * 3072;
    float4 a = ((const float4*)p)[t];
    float4 c = ((const float4*)(p + 1024))[t];
    float4 xr = ((const float4*)(X + row * 1024))[t];
    float x[4] = { a.x+c.x+xr.x, a.y+c.y+xr.y, a.z+c.z+xr.z, a.w+c.w+xr.w };
    ((float4*)(X2 + row * 1024))[t] = make_float4(x[0], x[1], x[2], x[3]);
    float s = x[0]+x[1]+x[2]+x[3];
    float q = x[0]*x[0]+x[1]*x[1]+x[2]*x[2]+x[3]*x[3];
#pragma unroll
    for (int o = 32; o > 0; o >>= 1) { s += __shfl_down(s, o, 64); q += __shfl_down(q, o, 64); }
    __shared__ float aS[4], aQ[4];
    if ((t & 63) == 0) { aS[t >> 6] = s; aQ[t >> 6] = q; }
    __syncthreads();
    s = aS[0]+aS[1]+aS[2]+aS[3];
    q = aQ[0]+aQ[1]+aQ[2]+aQ[3];
    float mean = s * (1.f/1024.f);
    float var  = q * (1.f/1024.f) - mean*mean;
    float rstd = rsqrtf(var + 1e-5f);
    float4 wv = ((const float4*)w)[t];
    float4 bv = ((const float4*)bb)[t];
    uint2 r;
    r.x = (u32)f2b((x[0]-mean)*rstd*wv.x + bv.x) | ((u32)f2b((x[1]-mean)*rstd*wv.y + bv.y) << 16);
    r.y = (u32)f2b((x[2]-mean)*rstd*wv.z + bv.z) | ((u32)f2b((x[3]-mean)*rstd*wv.w + bv.w) << 16);
    ((uint2*)(hb + row * 1024))[t] = r;
}

// ---------- combine FFN2 partials + bias + X2 -> d_out (fp32) ----------
__global__ __launch_bounds__(256) void ffn2_combine(const float* __restrict__ P,
                                                    const float* __restrict__ b2,
                                                    const float* __restrict__ X2,
                                                    float* __restrict__ out) {
    const long row = blockIdx.x;
    const int t = threadIdx.x;
    float4 p0 = ((const float4*)(P + row * 1024))[t];
    float4 p1 = ((const float4*)(P + 16777216 + row * 1024))[t];
    float4 x2 = ((const float4*)(X2 + row * 1024))[t];
    float4 bv = ((const float4*)b2)[t];
    ((float4*)(out + row * 1024))[t] = make_float4(
        p0.x + p1.x + x2.x + bv.x, p0.y + p1.y + x2.y + bv.y,
        p0.z + p1.z + x2.z + bv.z, p0.w + p1.w + x2.w + bv.w);
}

// ---------- MFMA GEMM, templated panel count (BK = PANELS*32) ----------
// C = A[M][K] @ Bt[N][K]^T, bf16->fp32->bf16. mb innermost (mb = pid & 31), M=4096.
// EPI_QKVG: rotary for c<2048 (via xtab in `bias`); V-range blocks (2048<=col0<4096)
// store DIRECTLY TRANSPOSED into Vt (B,H,256,S) and skip the row-major write.
// T2/T21 swizzle (validated R7: SQ_LDS_BANK_CONFLICT 6.29M -> 0): read slot' =
// quad ^ ((l16>>1)&3); staged content pre-permuted via global slot (t&3)^((t>>3)&3).
enum { EPI_GELU_BIAS = 2, EPI_QKVG = 4 };

template<int EPI, int PANELS>
__global__ __launch_bounds__(256) void mgemm(
    const u16* __restrict__ A, const u16* __restrict__ Bt, u16* __restrict__ Cv,
    int K, int aStride, long cStride,
    const float* __restrict__ bias, u16* __restrict__ Vt) {
    __shared__ __align__(16) u16 As[PANELS * 4096];
    __shared__ __align__(16) u16 Bs[PANELS * 4096];
    const int pid = blockIdx.x;
    const int mb = pid & 31;
    const int nb = pid >> 5;
    const int t = threadIdx.x;
    const int row0 = mb * 128, col0 = nb * 128;
    const int wave = t >> 6, lane = t & 63;
    const int wm = wave >> 1, wn = wave & 1;
    const int quad = lane >> 4, l16 = lane & 15;
    const int sgc = ((t & 3) ^ ((t >> 3) & 3)) * 8;     // stage-side swizzled column
    const u16* Ag = A + (long)(row0 + (t >> 2)) * aStride + sgc;
    const u16* Bg = Bt + (long)(col0 + (t >> 2)) * K + sgc;
    const long aj = (long)64 * aStride;
    const long bj = (long)64 * K;
    const u32 lo = __builtin_amdgcn_readfirstlane((u32)(wave * 1024));
    const int swr = ((l16 >> 1) & 3) << 3;              // read-side slot XOR (u16 units)

    f32x4 acc[4][4];
#pragma unroll
    for (int i = 0; i < 4; i++)
#pragma unroll
        for (int j = 0; j < 4; j++) acc[i][j] = (f32x4){0.f, 0.f, 0.f, 0.f};

    for (int k0 = 0; k0 < K; k0 += PANELS * 32) {
#pragma unroll
        for (int h = 0; h < PANELS; h++) {
            const u16* Agh = Ag + k0 + h * 32;
            const u16* Bgh = Bg + k0 + h * 32;
            async_ld16(Agh,      (const char*)As + h*8192 + lo);
            async_ld16(Agh + aj, (const char*)As + h*8192 + 4096 + lo);
            async_ld16(Bgh,      (const char*)Bs + h*8192 + lo);
            async_ld16(Bgh + bj, (const char*)Bs + h*8192 + 4096 + lo);
        }
        __syncthreads();
#pragma unroll
        for (int h = 0; h < PANELS; h++) {
            short8 af[4], bf[4];
#pragma unroll
            for (int mt = 0; mt < 4; mt++)
                af[mt] = *(const short8*)(As + h*4096 + (wm*64 + mt*16 + l16) * 32 + ((quad*8) ^ swr));
#pragma unroll
            for (int nt = 0; nt < 4; nt++)
                bf[nt] = *(const short8*)(Bs + h*4096 + (wn*64 + nt*16 + l16) * 32 + ((quad*8) ^ swr));
#pragma unroll
            for (int mt = 0; mt < 4; mt++)
#pragma unroll
                for (int nt = 0; nt < 4; nt++)
                    acc[mt][nt] = __builtin_amdgcn_mfma_f32_16x16x32_bf16(af[mt], bf[nt], acc[mt][nt], 0, 0, 0);
        }
        __syncthreads();
    }

    if constexpr (EPI == EPI_QKVG) {
        if (col0 >= 2048 && col0 < 4096) {
            // V blocks: store transposed into Vt (B,H,256,S). reg 0..3 = 4 consecutive s.
            const int bq = row0 >> 11;
            const int sb = (row0 & 2047) + wm*64 + quad*4;
#pragma unroll
            for (int mt = 0; mt < 4; mt++) {
#pragma unroll
                for (int nt = 0; nt < 4; nt++) {
                    int vc = (col0 - 2048) + wn*64 + nt*16 + l16;
                    u16* dst = Vt + ((long)((bq << 3) + (vc >> 8)) * 256 + (vc & 255)) * 2048
                                  + sb + mt*16;
                    uint2 pk;
                    pk.x = (u32)f2b(acc[mt][nt][0]) | ((u32)f2b(acc[mt][nt][1]) << 16);
                    pk.y = (u32)f2b(acc[mt][nt][2]) | ((u32)f2b(acc[mt][nt][3]) << 16);
                    *(uint2*)dst = pk;
                }
            }
            return;
        }
    }

#pragma unroll
    for (int mt = 0; mt < 4; mt++) {
#pragma unroll
        for (int reg = 0; reg < 4; reg++) {
            int r = row0 + wm*64 + mt*16 + quad*4 + reg;
#pragma unroll
            for (int nt = 0; nt < 4; nt++) {
                int c = col0 + wn*64 + nt*16 + l16;
                float v = acc[mt][nt][reg];
                if constexpr (EPI == EPI_GELU_BIAS) {
                    v = gelu_fast(v + bias[c]);
                } else if constexpr (EPI == EPI_QKVG) {
                    if (c < 2048) {  // xPos rotary: Q (c<1024, up) / K (else, down) via table
                        int j = (c & 127) >> 1;
                        float4 tb = ((const float4*)bias)[((r & 2047) << 6) + j];
                        float cs = (c < 1024) ? tb.x : tb.z;
                        float sn = (c < 1024) ? tb.y : tb.w;
                        float partner = __shfl_xor(v, 1, 64);
                        v = v * cs + ((c & 1) ? partner : -partner) * sn;
                    }
                }
                Cv[(long)r * cStride + c] = f2b(v);
            }
        }
    }
}

// ---------- split-K (x2) MFMA GEMM, BK=64, N=1024, fp32 partial out ----------
// Double-buffered ring (depth 2, T3 minimum recipe): issue next K-tile's
// global_load_lds BEFORE computing the current tile, wait with COUNTED
// vmcnt(8) (current tile's 8 loads retired; next tile's 8 stay in flight
// across the raw s_barrier). Rationale: only 2 blocks/CU (8 waves) here,
// so TLP can't hide the ~900cy HBM latency the old issue-then-drain paid
// per K-step. LDS 64 KiB (2 blocks/CU cap == grid). Same T21 swizzle.
__global__ __launch_bounds__(256) void mgemm_sk(
    const u16* __restrict__ A, const u16* __restrict__ Bt, float* __restrict__ P,
    int K, int kHalf, int aStride, long pRowStride, long sliceOff) {
    __shared__ __align__(16) u16 As[4 * 4096];   // [buf*2 + panel][4096]
    __shared__ __align__(16) u16 Bs[4 * 4096];
    const int pid = blockIdx.x;
    const int mb = pid & 31;
    const int nb = (pid & 255) >> 5;
    const int slice = pid >> 8;
    const int t = threadIdx.x;
    const int row0 = mb * 128, col0 = nb * 128;
    const int wave = t >> 6, lane = t & 63;
    const int wm = wave >> 1, wn = wave & 1;
    const int quad = lane >> 4, l16 = lane & 15;
    const int sgc = ((t & 3) ^ ((t >> 3) & 3)) * 8;     // stage-side swizzled column
    const u16* Ag = A + (long)(row0 + (t >> 2)) * aStride + sgc;
    const u16* Bg = Bt + (long)(col0 + (t >> 2)) * K + sgc;
    const long aj = (long)64 * aStride;
    const long bj = (long)64 * K;
    const u32 lo = __builtin_amdgcn_readfirstlane((u32)(wave * 1024));
    const int swr = ((l16 >> 1) & 3) << 3;              // read-side slot XOR (u16 units)

    f32x4 acc[4][4];
#pragma unroll
    for (int i = 0; i < 4; i++)
#pragma unroll
        for (int j = 0; j < 4; j++) acc[i][j] = (f32x4){0.f, 0.f, 0.f, 0.f};

    const int kBeg = slice * kHalf;
    const int nsteps = kHalf >> 6;

    // stage K-tile starting at k0 into LDS buffer bb (8 loads/thread-slot, wave-uniform)
    auto stage = [&](int k0, int bb) {
#pragma unroll
        for (int h = 0; h < 2; h++) {
            const u16* Agh = Ag + k0 + h * 32;
            const u16* Bgh = Bg + k0 + h * 32;
            async_ld16(Agh,      (const char*)As + bb*16384 + h*8192 + lo);
            async_ld16(Agh + aj, (const char*)As + bb*16384 + h*8192 + 4096 + lo);
            async_ld16(Bgh,      (const char*)Bs + bb*16384 + h*8192 + lo);
            async_ld16(Bgh + bj, (const char*)Bs + bb*16384 + h*8192 + 4096 + lo);
        }
    };

    stage(kBeg, 0);   // prologue: tile 0 -> buf 0
    for (int i = 0; i < nsteps; i++) {
        const int buf = i & 1;
        if (i + 1 < nsteps) {
            stage(kBeg + (i + 1) * 64, buf ^ 1);             // issue next first
            asm volatile("s_waitcnt vmcnt(8)" ::: "memory"); // current tile landed; next in flight
        } else {
            asm volatile("s_waitcnt vmcnt(0)" ::: "memory"); // last tile: full drain
        }
        __builtin_amdgcn_s_barrier();                        // all waves' stores visible
#pragma unroll
        for (int h = 0; h < 2; h++) {
            short8 af[4], bf[4];
#pragma unroll
            for (int mt = 0; mt < 4; mt++)
                af[mt] = *(const short8*)(As + buf*8192 + h*4096 + (wm*64 + mt*16 + l16) * 32 + ((quad*8) ^ swr));
#pragma unroll
            for (int nt = 0; nt < 4; nt++)
                bf[nt] = *(const short8*)(Bs + buf*8192 + h*4096 + (wn*64 + nt*16 + l16) * 32 + ((quad*8) ^ swr));
#pragma unroll
            for (int mt = 0; mt < 4; mt++)
#pragma unroll
                for (int nt = 0; nt < 4; nt++)
                    acc[mt][nt] = __builtin_amdgcn_mfma_f32_16x16x32_bf16(af[mt], bf[nt], acc[mt][nt], 0, 0, 0);
        }
        __builtin_amdgcn_s_barrier();   // guard: next iter stages into the buf just read
    }

    float* Pb = P + slice * sliceOff;
#pragma unroll
    for (int mt = 0; mt < 4; mt++) {
#pragma unroll
        for (int reg = 0; reg < 4; reg++) {
            int r = row0 + wm*64 + mt*16 + quad*4 + reg;
#pragma unroll
            for (int nt = 0; nt < 4; nt++) {
                int c = col0 + wn*64 + nt*16 + l16;
                Pb[(long)r * pRowStride + c] = acc[mt][nt][reg];
            }
        }
    }
}

// ---------- MFMA retention + fused groupnorm + fused silu-gate ----------
// grid 512 (1D). QKVG (B,S,6144): Q cols 0..1023, K 1024..2047, G 4096..6143.
// Writes gated = silu(G)*groupnorm(O) in-place over the G segment. Vt (B,H,256,S).
// T2/T21 swizzle on Qs/Ks/Vs (see R5 notes): read slot = quad ^ (l16&3) ^ ((l16>>2)&3),
// staged via global source column cb ^ ((c>>2)&3) ^ ((c>>4)&3).
__global__ __launch_bounds__(256) void retention_mfma(
    u16* __restrict__ QKVG, const u16* __restrict__ Vt,
    const float* __restrict__ gnw, const float* __restrict__ gnb) {
    __shared__ __align__(16) u16 Qs[4][64][32];
    __shared__ __align__(16) u16 Ks[2][4][32][32];
    __shared__ __align__(16) u16 Vs[2][256][32];
    __shared__ u16 Ss[64][40];
    const int id = blockIdx.x;
    const int halfg = id >> 8, r5 = id & 255;
    const int bh = r5 >> 4, i16 = r5 & 15;
    const int tile = halfg ? i16 : 31 - i16;   // pair (i, i+256) work = 68 steps const
    const int b = bh >> 3, h = bh & 7;
    const int t = threadIdx.x;
    const int wave = t >> 6, lane = t & 63, quad = lane >> 4, l16 = lane & 15;
    const u32 lo = __builtin_amdgcn_readfirstlane((u32)(wave * 1024));
    const u16* Qbase = QKVG + (long)b * 2048 * 6144 + h * 128;
    const u16* Kbase = Qbase + 1024;
    const u16* Vbase = Vt + (long)(b * 8 + h) * 256 * 2048;
    u16* Gseg = QKVG + (long)b * 2048 * 6144 + 4096 + h * 256;
    // read-side slot XOR, pre-scaled to u16 units (slot index * 8)
    const int sq8 = (((l16 & 3) ^ ((l16 >> 2) & 3))) << 3;

    float g = 1.f - expf(-3.4657359027997265f + (-0.3960841031771116f) * (float)h);
    float log2g = log2f(g);
    const float gi16 = exp2f(log2g * -16.f);   // γ^-16
    const float gi32 = gi16 * gi16;            // γ^-32 (per-step update)
    const float gf[4] = {1.f, g, g*g, g*g*g};
    const int srow0 = tile*64 + wave*16 + quad*4;
    float drun = exp2f(log2g * (float)(srow0 - l16));   // γ^(srow0 - l16) at jt=0

    auto issueKV = [&](int jt, int buf) {
#pragma unroll
        for (int i = 0; i < 2; i++) {
            int c = t + i * 256;
            int ks = c >> 7, row = (c >> 2) & 31;
            int cbs = (c & 3) ^ ((c >> 2) & 3) ^ ((c >> 4) & 3);   // inverse-swz source
            async_ld16(Kbase + (long)(jt*32 + row) * 6144 + ks*32 + cbs*8,
                       (const char*)Ks + buf*8192 + i*4096 + lo);
        }
#pragma unroll
        for (int i = 0; i < 4; i++) {
            int c = t + i * 256;
            int row = c >> 2;
            int cbs = (c & 3) ^ ((c >> 2) & 3) ^ ((c >> 4) & 3);
            async_ld16(Vbase + (long)row * 2048 + jt*32 + cbs*8,
                       (const char*)Vs + buf*16384 + i*4096 + lo);
        }
    };

    // prologue: Q tile + (K,V) for jt=0 into buf 0
#pragma unroll
    for (int i = 0; i < 4; i++) {
        int c = t + i * 256;
        int ks = c >> 8, row = (c >> 2) & 63;
        int cbs = (c & 3) ^ ((c >> 2) & 3) ^ ((c >> 4) & 3);
        async_ld16(Qbase + (long)(tile*64 + row) * 6144 + ks*32 + cbs*8,
                   (const char*)Qs + i*4096 + lo);
    }
    issueKV(0, 0);

    float gw[16], gbv[16];
#pragma unroll
    for (int nt = 0; nt < 16; nt++) {
        gw[nt]  = gnw[h*256 + nt*16 + l16];
        gbv[nt] = gnb[h*256 + nt*16 + l16];
    }
    f32x4 oacc[16];
#pragma unroll
    for (int nt = 0; nt < 16; nt++) oacc[nt] = (f32x4){0.f, 0.f, 0.f, 0.f};
    __syncthreads();

    const int njt = 2 * tile + 2;
    for (int jt = 0; jt < njt; jt++) {
        const int cur = jt & 1;
        if (jt + 1 < njt) issueKV(jt + 1, cur ^ 1);   // prefetch overlaps compute
        // QK^T (swizzled fragment reads: 2-way banks instead of 8-way)
        f32x4 s0 = (f32x4){0.f,0.f,0.f,0.f}, s1 = (f32x4){0.f,0.f,0.f,0.f};
#pragma unroll
        for (int ks = 0; ks < 4; ks++) {
            short8 aq = *(const short8*)&Qs[ks][wave*16 + l16][(quad*8) ^ sq8];
            short8 b0 = *(const short8*)&Ks[cur][ks][l16][(quad*8) ^ sq8];
            short8 b1 = *(const short8*)&Ks[cur][ks][16 + l16][(quad*8) ^ sq8];
            s0 = __builtin_amdgcn_mfma_f32_16x16x32_bf16(aq, b0, s0, 0, 0, 0);
            s1 = __builtin_amdgcn_mfma_f32_16x16x32_bf16(aq, b1, s1, 0, 0, 0);
        }
        // decay + causal mask -> Ss (wave-private rows: no barrier needed)
#pragma unroll
        for (int reg = 0; reg < 4; reg++) {
            int srow = srow0 + reg;
            int tc0 = jt*32 + l16, tc1 = tc0 + 16;
            float dbase = drun * gf[reg];               // γ^(srow - tc0)
            float d0 = (srow >= tc0) ? dbase : 0.f;
            float d1 = (srow >= tc1) ? dbase * gi16 : 0.f;
            Ss[wave*16 + quad*4 + reg][l16]      = f2b(s0[reg] * d0);
            Ss[wave*16 + quad*4 + reg][16 + l16] = f2b(s1[reg] * d1);
        }
        drun *= gi32;
        // PV: O[64x256] += S[64x32] @ V[32x256]
        short8 as = *(const short8*)&Ss[wave*16 + l16][quad*8];
#pragma unroll
        for (int nt = 0; nt < 16; nt++) {
            short8 bv = *(const short8*)&Vs[cur][nt*16 + l16][(quad*8) ^ sq8];
            oacc[nt] = __builtin_amdgcn_mfma_f32_16x16x32_bf16(as, bv, oacc[nt], 0, 0, 0);
        }
        __syncthreads();   // drains prefetch + guards buf reuse
    }

    // fused groupnorm + silu(G) gate, written in-place over G segment
#pragma unroll
    for (int reg = 0; reg < 4; reg++) {
        float s = 0.f, q = 0.f;
#pragma unroll
        for (int nt = 0; nt < 16; nt++) { float v = oacc[nt][reg]; s += v; q += v*v; }
#pragma unroll
        for (int m = 1; m < 16; m <<= 1) { s += __shfl_xor(s, m, 16); q += __shfl_xor(q, m, 16); }
        float mean = s * (1.f/256.f);
        float var  = q * (1.f/256.f) - mean*mean;
        float rstd = rsqrtf(var + 1e-5f);
        int srow = srow0 + reg;
        u16* grow = Gseg + (long)srow * 6144;
#pragma unroll
        for (int nt = 0; nt < 16; nt++) {
            float gval = b2f(grow[nt*16 + l16]);
            float y = (oacc[nt][reg] - mean) * rstd * gw[nt] + gbv[nt];
            float sg = gval / (1.f + exp2f(-1.4426950408889634f * gval));
            grow[nt*16 + l16] = f2b(sg * y);
        }
    }
}

extern "C" void kernel_launch(void* const* d_in, const int* in_sizes, int n_in,
                              void* d_out, int out_size, void* d_ws, size_t ws_size,
                              hipStream_t stream) {
    (void)in_sizes; (void)n_in; (void)out_size; (void)ws_size;
    const float* X    = (const float*)d_in[0];
    const float* Wq   = (const float*)d_in[1];
    const float* Wk   = (const float*)d_in[2];
    const float* Wv   = (const float*)d_in[3];
    const float* WG   = (const float*)d_in[4];
    const float* WO   = (const float*)d_in[5];
    const float* gnw  = (const float*)d_in[6];
    const float* gnb  = (const float*)d_in[7];
    const float* ln1w = (const float*)d_in[8];
    const float* ln1b = (const float*)d_in[9];
    const float* ln2w = (const float*)d_in[10];
    const float* ln2b = (const float*)d_in[11];
    const float* fw1  = (const float*)d_in[12];
    const float* fb1  = (const float*)d_in[13];
    const float* fw2  = (const float*)d_in[14];
    const float* fb2  = (const float*)d_in[15];

    constexpr int D = 1024, FFN = 4096;
    constexpr int M = 4096; // B*S rows
    constexpr long MB = 1048576;

    char* ws = (char*)d_ws;
    // weights (persistent until consumed):
    u16* WT   = (u16*)(ws + 0*MB);    // QKVG combined (6144,1024)  12 MB [..QKVG gemm]
    u16* WOT  = (u16*)(ws + 12*MB);   // (1024, 2048)                4 MB [..WO]
    u16* fw1T = (u16*)(ws + 16*MB);   // (4096, 1024)                8 MB [..FFN1]
    u16* fw2T = (u16*)(ws + 24*MB);   // (1024, 4096)                8 MB [..FFN2]
    // activations:
    u16*   QKVG = (u16*)(ws + 32*MB); // bf16 (B,S,6144) 48 MB [QKVG gemm .. WO]
                                      //   V segment row-major unused (V goes straight to Vt);
                                      //   WO parks fp32 partials in Q/K/V seg bytes of each row
    u16*   Xn   = (u16*)(ws + 80*MB); // bf16 (B,S,D)     8 MB [prep .. QKVG gemm]
    float4* xtab= (float4*)(ws + 88*MB);// fp32 table     2 MB [prep .. QKVG gemm]
    u16*   Vt   = (u16*)(ws + 90*MB); // bf16 (B,H,256,S)16 MB [QKVG gemm .. retention]
    float* X2   = (float*)(ws + 80*MB);//fp32 (B,S,D)    16 MB [ln2_combine .. ffn2_combine] (reuses Xn+xtab+Vt head)
    u16*   hb   = (u16*)(ws + 0*MB);  // bf16 (B,S,D)     8 MB [ln2_combine .. FFN1] (reuses WT)
    u16*   mid  = (u16*)(ws + 32*MB); // bf16 (B,S,FFN)  32 MB [FFN1 .. FFN2]        (reuses QKVG)
    float* PF   = (float*)(ws + 0*MB);// FFN2 partials: P0 [0,16), P1 [64,80) MB

    // 1. fused prep: 7x weight transpose + xPos table + LN1
    prep_k<<<20992, 256, 0, stream>>>(Wq, Wk, Wv, WG, WO, fw1, fw2, X, ln1w, ln1b,
                                      WT, WOT, fw1T, fw2T, xtab, Xn);
    // 2. fused QKVG projection + xPos epilogue; V blocks stored transposed into Vt [BK=32]
    mgemm<EPI_QKVG, 1><<<1536, 256, 0, stream>>>(
        Xn, WT, QKVG, D, D, 6144, (const float*)xtab, Vt);
    // 3. retention + groupnorm + silu-gate -> in-place on G segment [LDS swizzled]
    retention_mfma<<<512, 256, 0, stream>>>(QKVG, Vt, gnw, gnb);
    // 4. WO split-K x2: partials into dead Q/K/V segment bytes of QKVG rows  [BK=64, dbuf ring]
    mgemm_sk<<<512, 256, 0, stream>>>(
        QKVG + 4096, WOT, (float*)QKVG, 2048, 1024, 6144, 3072, 1024);
    // 5. combine + residual + LN2 -> X2 (fp32) and hb (bf16)
    ln2_combine<<<M, 256, 0, stream>>>((const float*)QKVG, X, ln2w, ln2b, X2, hb);
    // 6. mid = gelu_fast(hb @ W1 + b1)  bf16  [BK=64]
    mgemm<EPI_GELU_BIAS, 2><<<1024, 256, 0, stream>>>(
        hb, fw1T, mid, D, D, FFN, fb1, nullptr);
    // 7. FFN2 split-K x2: partials P0 [0,16), P1 [64,80) MB  [BK=64, dbuf ring]
    mgemm_sk<<<512, 256, 0, stream>>>(
        mid, fw2T, PF, 4096, 2048, 4096, 1024, 16777216);
    // 8. combine + bias + X2 residual -> d_out (fp32)
    ffn2_combine<<<M, 256, 0, stream>>>(PF, fb2, X2, (float*)d_out);
}

// Round 9
// 412.709 us; speedup vs baseline: 1.0957x; 1.0487x over previous
//
#include <hip/hip_runtime.h>
#include <hip/hip_bf16.h>

typedef unsigned short u16;
typedef unsigned int   u32;
typedef short short8 __attribute__((ext_vector_type(8)));
typedef float f32x4  __attribute__((ext_vector_type(4)));

// ---------- bf16 helpers ----------
__device__ __forceinline__ float b2f(u16 u) { return __uint_as_float(((u32)u) << 16); }
__device__ __forceinline__ u16 f2b(float f) {
    u32 u = __float_as_uint(f);
    u += 0x7FFF + ((u >> 16) & 1);   // RTNE
    return (u16)(u >> 16);
}
// fast gelu (tanh form), |err| < 4e-4 (far below bf16 storage rounding)
__device__ __forceinline__ float gelu_fast(float v) {
    float a = v * (2.302118f + 0.102953f * v * v);   // 2*log2e*0.79788456*(1+0.044715 v^2)
    a = fminf(a, 120.f);                              // avoid inf/inf for v > ~10.8
    float e = exp2f(a);
    return v * e / (1.f + e);
}

// ---------- async global->LDS 16B (wave-uniform LDS base + lane*16) ----------
typedef const unsigned int __attribute__((address_space(1)))* gas1;
typedef unsigned int __attribute__((address_space(3)))* las3;
__device__ __forceinline__ void async_ld16(const void* g, const void* l) {
    __builtin_amdgcn_global_load_lds((gas1)(unsigned long long)g,
                                     (las3)(unsigned int)(unsigned long long)l,
                                     16, 0, 0);
}

// ================= fused prep: 7x wtrans + xPos table + LN1 =================
__device__ __forceinline__ void wtrans_body(const float* __restrict__ W, u16* __restrict__ Wt,
                                            int K, int N, int bx, int by, int bz) {
    __shared__ u16 tile[32][36];
    const int k0 = bx * 32, n0 = by * 32;
    const float* Wz = W + (long)bz * K * N;
    u16* Wtz = Wt + (long)bz * K * N;
    const int t = threadIdx.x;
    const int r = t >> 3, c = (t & 7) * 4;
    float4 v = *(const float4*)(Wz + (long)(k0 + r) * N + n0 + c);
    tile[r][c+0] = f2b(v.x); tile[r][c+1] = f2b(v.y);
    tile[r][c+2] = f2b(v.z); tile[r][c+3] = f2b(v.w);
    __syncthreads();
    uint2 pk;
    pk.x = (u32)tile[c+0][r] | ((u32)tile[c+1][r] << 16);
    pk.y = (u32)tile[c+2][r] | ((u32)tile[c+3][r] << 16);
    *(uint2*)(Wtz + (long)(n0 + r) * K + k0 + c) = pk;
}

__device__ __forceinline__ void xtab_body(float4* __restrict__ tab, int blk) {
    int idx = blk * 256 + threadIdx.x;   // 0..131071
    int j = idx & 63, s = idx >> 6;
    float sv = (2.f * j + 51.2f) / 179.2f;
    float scale = exp2f(log2f(sv) * ((float)s * (1.f / 512.f)));
    float inv_freq = exp2f((float)j * (-13.287712379549449f / 64.f));
    float ang = (float)s * inv_freq;
    float sn = sinf(ang), cs = cosf(ang);
    tab[idx] = make_float4(cs * scale, sn * scale, cs / scale, sn / scale);
}

__device__ __forceinline__ void ln_body(const float* __restrict__ X,
                                        const float* __restrict__ w,
                                        const float* __restrict__ bb,
                                        u16* __restrict__ out, long row) {
    const int t = threadIdx.x;
    float4 p = ((const float4*)(X + row * 1024))[t];
    float x[4] = { p.x, p.y, p.z, p.w };
    float s = x[0]+x[1]+x[2]+x[3];
    float q = x[0]*x[0]+x[1]*x[1]+x[2]*x[2]+x[3]*x[3];
#pragma unroll
    for (int o = 32; o > 0; o >>= 1) { s += __shfl_down(s, o, 64); q += __shfl_down(q, o, 64); }
    __shared__ float aS[4], aQ[4];
    if ((t & 63) == 0) { aS[t >> 6] = s; aQ[t >> 6] = q; }
    __syncthreads();
    s = aS[0]+aS[1]+aS[2]+aS[3];
    q = aQ[0]+aQ[1]+aQ[2]+aQ[3];
    float mean = s * (1.f/1024.f);
    float var  = q * (1.f/1024.f) - mean*mean;
    float rstd = rsqrtf(var + 1e-5f);
    float4 wv = ((const float4*)w)[t];
    float4 bv = ((const float4*)bb)[t];
    uint2 r;
    r.x = (u32)f2b((x[0]-mean)*rstd*wv.x + bv.x) | ((u32)f2b((x[1]-mean)*rstd*wv.y + bv.y) << 16);
    r.y = (u32)f2b((x[2]-mean)*rstd*wv.z + bv.z) | ((u32)f2b((x[3]-mean)*rstd*wv.w + bv.w) << 16);
    ((uint2*)(out + row * 1024))[t] = r;
}

__global__ __launch_bounds__(256) void prep_k(
    const float* __restrict__ Wq, const float* __restrict__ Wk,
    const float* __restrict__ Wv, const float* __restrict__ WG,
    const float* __restrict__ WO, const float* __restrict__ fw1,
    const float* __restrict__ fw2, const float* __restrict__ X,
    const float* __restrict__ ln1w, const float* __restrict__ ln1b,
    u16* __restrict__ WT, u16* __restrict__ WOT,
    u16* __restrict__ fw1T, u16* __restrict__ fw2T,
    float4* __restrict__ xtab, u16* __restrict__ Xn) {
    const int id = blockIdx.x;
    if (id < 16384) {
        const float* W; u16* Wt; int K, N, bx, by, bz = 0;
        if (id < 1024)       { W=Wq;  Wt=WT;           K=1024; N=128;  int l=id;       bx=l&31;  by=(l>>5)&3; bz=l>>7; }
        else if (id < 2048)  { W=Wk;  Wt=WT+1048576;   K=1024; N=128;  int l=id-1024;  bx=l&31;  by=(l>>5)&3; bz=l>>7; }
        else if (id < 4096)  { W=Wv;  Wt=WT+2097152;   K=1024; N=256;  int l=id-2048;  bx=l&31;  by=(l>>5)&7; bz=l>>8; }
        else if (id < 6144)  { W=WG;  Wt=WT+4194304;   K=1024; N=2048; int l=id-4096;  bx=l&31;  by=l>>5; }
        else if (id < 8192)  { W=WO;  Wt=WOT;          K=2048; N=1024; int l=id-6144;  bx=l&63;  by=l>>6; }
        else if (id < 12288) { W=fw1; Wt=fw1T;         K=1024; N=4096; int l=id-8192;  bx=l&31;  by=l>>5; }
        else                 { W=fw2; Wt=fw2T;         K=4096; N=1024; int l=id-12288; bx=l&127; by=l>>7; }
        wtrans_body(W, Wt, K, N, bx, by, bz);
    } else if (id < 16896) {
        xtab_body(xtab, id - 16384);
    } else {
        ln_body(X, ln1w, ln1b, Xn, id - 16896);
    }
}

// ---------- combine WO partials + residual X, then LN2 -> X2 (fp32) and hb (bf16) ----------
__global__ __launch_bounds__(256) void ln2_combine(const float* __restrict__ P,
                                                   const float* __restrict__ X,
                                                   const float* __restrict__ w,
                                                   const float* __restrict__ bb,
                                                   float* __restrict__ X2,
                                                   u16* __restrict__ hb) {
    const long row = blockIdx.x;
    const int t = threadIdx.x;
    const float* p = P + row * 3072;
    float4 a = ((const float4*)p)[t];
    float4 c = ((const float4*)(p + 1024))[t];
    float4 xr = ((const float4*)(X + row * 1024))[t];
    float x[4] = { a.x+c.x+xr.x, a.y+c.y+xr.y, a.z+c.z+xr.z, a.w+c.w+xr.w };
    ((float4*)(X2 + row * 1024))[t] = make_float4(x[0], x[1], x[2], x[3]);
    float s = x[0]+x[1]+x[2]+x[3];
    float q = x[0]*x[0]+x[1]*x[1]+x[2]*x[2]+x[3]*x[3];
#pragma unroll
    for (int o = 32; o > 0; o >>= 1) { s += __shfl_down(s, o, 64); q += __shfl_down(q, o, 64); }
    __shared__ float aS[4], aQ[4];
    if ((t & 63) == 0) { aS[t >> 6] = s; aQ[t >> 6] = q; }
    __syncthreads();
    s = aS[0]+aS[1]+aS[2]+aS[3];
    q = aQ[0]+aQ[1]+aQ[2]+aQ[3];
    float mean = s * (1.f/1024.f);
    float var  = q * (1.f/1024.f) - mean*mean;
    float rstd = rsqrtf(var + 1e-5f);
    float4 wv = ((const float4*)w)[t];
    float4 bv = ((const float4*)bb)[t];
    uint2 r;
    r.x = (u32)f2b((x[0]-mean)*rstd*wv.x + bv.x) | ((u32)f2b((x[1]-mean)*rstd*wv.y + bv.y) << 16);
    r.y = (u32)f2b((x[2]-mean)*rstd*wv.z + bv.z) | ((u32)f2b((x[3]-mean)*rstd*wv.w + bv.w) << 16);
    ((uint2*)(hb + row * 1024))[t] = r;
}

// ---------- combine FFN2 partials + bias + X2 -> d_out (fp32) ----------
__global__ __launch_bounds__(256) void ffn2_combine(const float* __restrict__ P,
                                                    const float* __restrict__ b2,
                                                    const float* __restrict__ X2,
                                                    float* __restrict__ out) {
    const long row = blockIdx.x;
    const int t = threadIdx.x;
    float4 p0 = ((const float4*)(P + row * 1024))[t];
    float4 p1 = ((const float4*)(P + 16777216 + row * 1024))[t];
    float4 x2 = ((const float4*)(X2 + row * 1024))[t];
    float4 bv = ((const float4*)b2)[t];
    ((float4*)(out + row * 1024))[t] = make_float4(
        p0.x + p1.x + x2.x + bv.x, p0.y + p1.y + x2.y + bv.y,
        p0.z + p1.z + x2.z + bv.z, p0.w + p1.w + x2.w + bv.w);
}

// ---------- MFMA GEMM, BK=32 double-buffered ring ----------
// C = A[M][K] @ Bt[N][K]^T, bf16->fp32->bf16. mb innermost (mb = pid & 31), M=4096.
// Ring (validated R8 on mgemm_sk): issue next K-tile's 4 global_load_lds BEFORE
// computing current tile; COUNTED s_waitcnt vmcnt(4) -> current tile's loads
// retired, next tile's stay in flight across the raw s_barrier. LDS 32 KiB
// (2 bufs), occupancy 5 blocks/CU (vs 6 at single-buf: accepted for the cover).
// T2/T21 swizzle (validated R7: conflicts 6.29M -> 0): read slot' =
// quad ^ ((l16>>1)&3); staged content pre-permuted via global slot (t&3)^((t>>3)&3).
// EPI_QKVG: rotary for c<2048 (via xtab in `bias`); V-range blocks (2048<=col0<4096)
// store DIRECTLY TRANSPOSED into Vt (B,H,256,S) and skip the row-major write.
enum { EPI_GELU_BIAS = 2, EPI_QKVG = 4 };

template<int EPI>
__global__ __launch_bounds__(256) void mgemm(
    const u16* __restrict__ A, const u16* __restrict__ Bt, u16* __restrict__ Cv,
    int K, int aStride, long cStride,
    const float* __restrict__ bias, u16* __restrict__ Vt) {
    __shared__ __align__(16) u16 As[2 * 4096];   // [buf][4096]
    __shared__ __align__(16) u16 Bs[2 * 4096];
    const int pid = blockIdx.x;
    const int mb = pid & 31;
    const int nb = pid >> 5;
    const int t = threadIdx.x;
    const int row0 = mb * 128, col0 = nb * 128;
    const int wave = t >> 6, lane = t & 63;
    const int wm = wave >> 1, wn = wave & 1;
    const int quad = lane >> 4, l16 = lane & 15;
    const int sgc = ((t & 3) ^ ((t >> 3) & 3)) * 8;     // stage-side swizzled column
    const u16* Ag = A + (long)(row0 + (t >> 2)) * aStride + sgc;
    const u16* Bg = Bt + (long)(col0 + (t >> 2)) * K + sgc;
    const long aj = (long)64 * aStride;
    const long bj = (long)64 * K;
    const u32 lo = __builtin_amdgcn_readfirstlane((u32)(wave * 1024));
    const int swr = ((l16 >> 1) & 3) << 3;              // read-side slot XOR (u16 units)

    f32x4 acc[4][4];
#pragma unroll
    for (int i = 0; i < 4; i++)
#pragma unroll
        for (int j = 0; j < 4; j++) acc[i][j] = (f32x4){0.f, 0.f, 0.f, 0.f};

    // stage the 32-wide K-slice at k0 into LDS buffer bb (4 loads)
    auto stage = [&](int k0, int bb) {
        const u16* Agh = Ag + k0;
        const u16* Bgh = Bg + k0;
        async_ld16(Agh,      (const char*)As + bb*8192 + lo);
        async_ld16(Agh + aj, (const char*)As + bb*8192 + 4096 + lo);
        async_ld16(Bgh,      (const char*)Bs + bb*8192 + lo);
        async_ld16(Bgh + bj, (const char*)Bs + bb*8192 + 4096 + lo);
    };

    const int nT = K >> 5;
    stage(0, 0);   // prologue: tile 0 -> buf 0
    for (int i = 0; i < nT; i++) {
        const int buf = i & 1;
        if (i + 1 < nT) {
            stage((i + 1) * 32, buf ^ 1);                    // issue next first
            asm volatile("s_waitcnt vmcnt(4)" ::: "memory"); // current tile landed; next in flight
        } else {
            asm volatile("s_waitcnt vmcnt(0)" ::: "memory"); // last tile: full drain
        }
        __builtin_amdgcn_s_barrier();                        // all waves' stores visible
        short8 af[4], bf[4];
#pragma unroll
        for (int mt = 0; mt < 4; mt++)
            af[mt] = *(const short8*)(As + buf*4096 + (wm*64 + mt*16 + l16) * 32 + ((quad*8) ^ swr));
#pragma unroll
        for (int nt = 0; nt < 4; nt++)
            bf[nt] = *(const short8*)(Bs + buf*4096 + (wn*64 + nt*16 + l16) * 32 + ((quad*8) ^ swr));
#pragma unroll
        for (int mt = 0; mt < 4; mt++)
#pragma unroll
            for (int nt = 0; nt < 4; nt++)
                acc[mt][nt] = __builtin_amdgcn_mfma_f32_16x16x32_bf16(af[mt], bf[nt], acc[mt][nt], 0, 0, 0);
        __builtin_amdgcn_s_barrier();   // guard: next iter stages into the buf just read
    }

    if constexpr (EPI == EPI_QKVG) {
        if (col0 >= 2048 && col0 < 4096) {
            // V blocks: store transposed into Vt (B,H,256,S). reg 0..3 = 4 consecutive s.
            const int bq = row0 >> 11;
            const int sb = (row0 & 2047) + wm*64 + quad*4;
#pragma unroll
            for (int mt = 0; mt < 4; mt++) {
#pragma unroll
                for (int nt = 0; nt < 4; nt++) {
                    int vc = (col0 - 2048) + wn*64 + nt*16 + l16;
                    u16* dst = Vt + ((long)((bq << 3) + (vc >> 8)) * 256 + (vc & 255)) * 2048
                                  + sb + mt*16;
                    uint2 pk;
                    pk.x = (u32)f2b(acc[mt][nt][0]) | ((u32)f2b(acc[mt][nt][1]) << 16);
                    pk.y = (u32)f2b(acc[mt][nt][2]) | ((u32)f2b(acc[mt][nt][3]) << 16);
                    *(uint2*)dst = pk;
                }
            }
            return;
        }
    }

#pragma unroll
    for (int mt = 0; mt < 4; mt++) {
#pragma unroll
        for (int reg = 0; reg < 4; reg++) {
            int r = row0 + wm*64 + mt*16 + quad*4 + reg;
#pragma unroll
            for (int nt = 0; nt < 4; nt++) {
                int c = col0 + wn*64 + nt*16 + l16;
                float v = acc[mt][nt][reg];
                if constexpr (EPI == EPI_GELU_BIAS) {
                    v = gelu_fast(v + bias[c]);
                } else if constexpr (EPI == EPI_QKVG) {
                    if (c < 2048) {  // xPos rotary: Q (c<1024, up) / K (else, down) via table
                        int j = (c & 127) >> 1;
                        float4 tb = ((const float4*)bias)[((r & 2047) << 6) + j];
                        float cs = (c < 1024) ? tb.x : tb.z;
                        float sn = (c < 1024) ? tb.y : tb.w;
                        float partner = __shfl_xor(v, 1, 64);
                        v = v * cs + ((c & 1) ? partner : -partner) * sn;
                    }
                }
                Cv[(long)r * cStride + c] = f2b(v);
            }
        }
    }
}

// ---------- split-K (x2) MFMA GEMM, BK=64, N=1024, fp32 partial out ----------
// Double-buffered ring (depth 2, validated R8): issue next K-tile's loads
// BEFORE computing the current tile; counted vmcnt(8). LDS 64 KiB. T21 swizzle.
__global__ __launch_bounds__(256) void mgemm_sk(
    const u16* __restrict__ A, const u16* __restrict__ Bt, float* __restrict__ P,
    int K, int kHalf, int aStride, long pRowStride, long sliceOff) {
    __shared__ __align__(16) u16 As[4 * 4096];   // [buf*2 + panel][4096]
    __shared__ __align__(16) u16 Bs[4 * 4096];
    const int pid = blockIdx.x;
    const int mb = pid & 31;
    const int nb = (pid & 255) >> 5;
    const int slice = pid >> 8;
    const int t = threadIdx.x;
    const int row0 = mb * 128, col0 = nb * 128;
    const int wave = t >> 6, lane = t & 63;
    const int wm = wave >> 1, wn = wave & 1;
    const int quad = lane >> 4, l16 = lane & 15;
    const int sgc = ((t & 3) ^ ((t >> 3) & 3)) * 8;     // stage-side swizzled column
    const u16* Ag = A + (long)(row0 + (t >> 2)) * aStride + sgc;
    const u16* Bg = Bt + (long)(col0 + (t >> 2)) * K + sgc;
    const long aj = (long)64 * aStride;
    const long bj = (long)64 * K;
    const u32 lo = __builtin_amdgcn_readfirstlane((u32)(wave * 1024));
    const int swr = ((l16 >> 1) & 3) << 3;              // read-side slot XOR (u16 units)

    f32x4 acc[4][4];
#pragma unroll
    for (int i = 0; i < 4; i++)
#pragma unroll
        for (int j = 0; j < 4; j++) acc[i][j] = (f32x4){0.f, 0.f, 0.f, 0.f};

    const int kBeg = slice * kHalf;
    const int nsteps = kHalf >> 6;

    // stage K-tile starting at k0 into LDS buffer bb (8 loads/thread-slot, wave-uniform)
    auto stage = [&](int k0, int bb) {
#pragma unroll
        for (int h = 0; h < 2; h++) {
            const u16* Agh = Ag + k0 + h * 32;
            const u16* Bgh = Bg + k0 + h * 32;
            async_ld16(Agh,      (const char*)As + bb*16384 + h*8192 + lo);
            async_ld16(Agh + aj, (const char*)As + bb*16384 + h*8192 + 4096 + lo);
            async_ld16(Bgh,      (const char*)Bs + bb*16384 + h*8192 + lo);
            async_ld16(Bgh + bj, (const char*)Bs + bb*16384 + h*8192 + 4096 + lo);
        }
    };

    stage(kBeg, 0);   // prologue: tile 0 -> buf 0
    for (int i = 0; i < nsteps; i++) {
        const int buf = i & 1;
        if (i + 1 < nsteps) {
            stage(kBeg + (i + 1) * 64, buf ^ 1);             // issue next first
            asm volatile("s_waitcnt vmcnt(8)" ::: "memory"); // current tile landed; next in flight
        } else {
            asm volatile("s_waitcnt vmcnt(0)" ::: "memory"); // last tile: full drain
        }
        __builtin_amdgcn_s_barrier();                        // all waves' stores visible
#pragma unroll
        for (int h = 0; h < 2; h++) {
            short8 af[4], bf[4];
#pragma unroll
            for (int mt = 0; mt < 4; mt++)
                af[mt] = *(const short8*)(As + buf*8192 + h*4096 + (wm*64 + mt*16 + l16) * 32 + ((quad*8) ^ swr));
#pragma unroll
            for (int nt = 0; nt < 4; nt++)
                bf[nt] = *(const short8*)(Bs + buf*8192 + h*4096 + (wn*64 + nt*16 + l16) * 32 + ((quad*8) ^ swr));
#pragma unroll
            for (int mt = 0; mt < 4; mt++)
#pragma unroll
                for (int nt = 0; nt < 4; nt++)
                    acc[mt][nt] = __builtin_amdgcn_mfma_f32_16x16x32_bf16(af[mt], bf[nt], acc[mt][nt], 0, 0, 0);
        }
        __builtin_amdgcn_s_barrier();   // guard: next iter stages into the buf just read
    }

    float* Pb = P + slice * sliceOff;
#pragma unroll
    for (int mt = 0; mt < 4; mt++) {
#pragma unroll
        for (int reg = 0; reg < 4; reg++) {
            int r = row0 + wm*64 + mt*16 + quad*4 + reg;
#pragma unroll
            for (int nt = 0; nt < 4; nt++) {
                int c = col0 + wn*64 + nt*16 + l16;
                Pb[(long)r * pRowStride + c] = acc[mt][nt][reg];
            }
        }
    }
}

// ---------- MFMA retention + fused groupnorm + fused silu-gate ----------
// grid 512 (1D). QKVG (B,S,6144): Q cols 0..1023, K 1024..2047, G 4096..6143.
// Writes gated = silu(G)*groupnorm(O) in-place over the G segment. Vt (B,H,256,S).
// T2/T21 swizzle on Qs/Ks/Vs (see R5 notes): read slot = quad ^ (l16&3) ^ ((l16>>2)&3),
// staged via global source column cb ^ ((c>>2)&3) ^ ((c>>4)&3).
__global__ __launch_bounds__(256) void retention_mfma(
    u16* __restrict__ QKVG, const u16* __restrict__ Vt,
    const float* __restrict__ gnw, const float* __restrict__ gnb) {
    __shared__ __align__(16) u16 Qs[4][64][32];
    __shared__ __align__(16) u16 Ks[2][4][32][32];
    __shared__ __align__(16) u16 Vs[2][256][32];
    __shared__ u16 Ss[64][40];
    const int id = blockIdx.x;
    const int halfg = id >> 8, r5 = id & 255;
    const int bh = r5 >> 4, i16 = r5 & 15;
    const int tile = halfg ? i16 : 31 - i16;   // pair (i, i+256) work = 68 steps const
    const int b = bh >> 3, h = bh & 7;
    const int t = threadIdx.x;
    const int wave = t >> 6, lane = t & 63, quad = lane >> 4, l16 = lane & 15;
    const u32 lo = __builtin_amdgcn_readfirstlane((u32)(wave * 1024));
    const u16* Qbase = QKVG + (long)b * 2048 * 6144 + h * 128;
    const u16* Kbase = Qbase + 1024;
    const u16* Vbase = Vt + (long)(b * 8 + h) * 256 * 2048;
    u16* Gseg = QKVG + (long)b * 2048 * 6144 + 4096 + h * 256;
    // read-side slot XOR, pre-scaled to u16 units (slot index * 8)
    const int sq8 = (((l16 & 3) ^ ((l16 >> 2) & 3))) << 3;

    float g = 1.f - expf(-3.4657359027997265f + (-0.3960841031771116f) * (float)h);
    float log2g = log2f(g);
    const float gi16 = exp2f(log2g * -16.f);   // γ^-16
    const float gi32 = gi16 * gi16;            // γ^-32 (per-step update)
    const float gf[4] = {1.f, g, g*g, g*g*g};
    const int srow0 = tile*64 + wave*16 + quad*4;
    float drun = exp2f(log2g * (float)(srow0 - l16));   // γ^(srow0 - l16) at jt=0

    auto issueKV = [&](int jt, int buf) {
#pragma unroll
        for (int i = 0; i < 2; i++) {
            int c = t + i * 256;
            int ks = c >> 7, row = (c >> 2) & 31;
            int cbs = (c & 3) ^ ((c >> 2) & 3) ^ ((c >> 4) & 3);   // inverse-swz source
            async_ld16(Kbase + (long)(jt*32 + row) * 6144 + ks*32 + cbs*8,
                       (const char*)Ks + buf*8192 + i*4096 + lo);
        }
#pragma unroll
        for (int i = 0; i < 4; i++) {
            int c = t + i * 256;
            int row = c >> 2;
            int cbs = (c & 3) ^ ((c >> 2) & 3) ^ ((c >> 4) & 3);
            async_ld16(Vbase + (long)row * 2048 + jt*32 + cbs*8,
                       (const char*)Vs + buf*16384 + i*4096 + lo);
        }
    };

    // prologue: Q tile + (K,V) for jt=0 into buf 0
#pragma unroll
    for (int i = 0; i < 4; i++) {
        int c = t + i * 256;
        int ks = c >> 8, row = (c >> 2) & 63;
        int cbs = (c & 3) ^ ((c >> 2) & 3) ^ ((c >> 4) & 3);
        async_ld16(Qbase + (long)(tile*64 + row) * 6144 + ks*32 + cbs*8,
                   (const char*)Qs + i*4096 + lo);
    }
    issueKV(0, 0);

    float gw[16], gbv[16];
#pragma unroll
    for (int nt = 0; nt < 16; nt++) {
        gw[nt]  = gnw[h*256 + nt*16 + l16];
        gbv[nt] = gnb[h*256 + nt*16 + l16];
    }
    f32x4 oacc[16];
#pragma unroll
    for (int nt = 0; nt < 16; nt++) oacc[nt] = (f32x4){0.f, 0.f, 0.f, 0.f};
    __syncthreads();

    const int njt = 2 * tile + 2;
    for (int jt = 0; jt < njt; jt++) {
        const int cur = jt & 1;
        if (jt + 1 < njt) issueKV(jt + 1, cur ^ 1);   // prefetch overlaps compute
        // QK^T (swizzled fragment reads: 2-way banks instead of 8-way)
        f32x4 s0 = (f32x4){0.f,0.f,0.f,0.f}, s1 = (f32x4){0.f,0.f,0.f,0.f};
#pragma unroll
        for (int ks = 0; ks < 4; ks++) {
            short8 aq = *(const short8*)&Qs[ks][wave*16 + l16][(quad*8) ^ sq8];
            short8 b0 = *(const short8*)&Ks[cur][ks][l16][(quad*8) ^ sq8];
            short8 b1 = *(const short8*)&Ks[cur][ks][16 + l16][(quad*8) ^ sq8];
            s0 = __builtin_amdgcn_mfma_f32_16x16x32_bf16(aq, b0, s0, 0, 0, 0);
            s1 = __builtin_amdgcn_mfma_f32_16x16x32_bf16(aq, b1, s1, 0, 0, 0);
        }
        // decay + causal mask -> Ss (wave-private rows: no barrier needed)
#pragma unroll
        for (int reg = 0; reg < 4; reg++) {
            int srow = srow0 + reg;
            int tc0 = jt*32 + l16, tc1 = tc0 + 16;
            float dbase = drun * gf[reg];               // γ^(srow - tc0)
            float d0 = (srow >= tc0) ? dbase : 0.f;
            float d1 = (srow >= tc1) ? dbase * gi16 : 0.f;
            Ss[wave*16 + quad*4 + reg][l16]      = f2b(s0[reg] * d0);
            Ss[wave*16 + quad*4 + reg][16 + l16] = f2b(s1[reg] * d1);
        }
        drun *= gi32;
        // PV: O[64x256] += S[64x32] @ V[32x256]
        short8 as = *(const short8*)&Ss[wave*16 + l16][quad*8];
#pragma unroll
        for (int nt = 0; nt < 16; nt++) {
            short8 bv = *(const short8*)&Vs[cur][nt*16 + l16][(quad*8) ^ sq8];
            oacc[nt] = __builtin_amdgcn_mfma_f32_16x16x32_bf16(as, bv, oacc[nt], 0, 0, 0);
        }
        __syncthreads();   // drains prefetch + guards buf reuse
    }

    // fused groupnorm + silu(G) gate, written in-place over G segment
#pragma unroll
    for (int reg = 0; reg < 4; reg++) {
        float s = 0.f, q = 0.f;
#pragma unroll
        for (int nt = 0; nt < 16; nt++) { float v = oacc[nt][reg]; s += v; q += v*v; }
#pragma unroll
        for (int m = 1; m < 16; m <<= 1) { s += __shfl_xor(s, m, 16); q += __shfl_xor(q, m, 16); }
        float mean = s * (1.f/256.f);
        float var  = q * (1.f/256.f) - mean*mean;
        float rstd = rsqrtf(var + 1e-5f);
        int srow = srow0 + reg;
        u16* grow = Gseg + (long)srow * 6144;
#pragma unroll
        for (int nt = 0; nt < 16; nt++) {
            float gval = b2f(grow[nt*16 + l16]);
            float y = (oacc[nt][reg] - mean) * rstd * gw[nt] + gbv[nt];
            float sg = gval / (1.f + exp2f(-1.4426950408889634f * gval));
            grow[nt*16 + l16] = f2b(sg * y);
        }
    }
}

extern "C" void kernel_launch(void* const* d_in, const int* in_sizes, int n_in,
                              void* d_out, int out_size, void* d_ws, size_t ws_size,
                              hipStream_t stream) {
    (void)in_sizes; (void)n_in; (void)out_size; (void)ws_size;
    const float* X    = (const float*)d_in[0];
    const float* Wq   = (const float*)d_in[1];
    const float* Wk   = (const float*)d_in[2];
    const float* Wv   = (const float*)d_in[3];
    const float* WG   = (const float*)d_in[4];
    const float* WO   = (const float*)d_in[5];
    const float* gnw  = (const float*)d_in[6];
    const float* gnb  = (const float*)d_in[7];
    const float* ln1w = (const float*)d_in[8];
    const float* ln1b = (const float*)d_in[9];
    const float* ln2w = (const float*)d_in[10];
    const float* ln2b = (const float*)d_in[11];
    const float* fw1  = (const float*)d_in[12];
    const float* fb1  = (const float*)d_in[13];
    const float* fw2  = (const float*)d_in[14];
    const float* fb2  = (const float*)d_in[15];

    constexpr int D = 1024, FFN = 4096;
    constexpr int M = 4096; // B*S rows
    constexpr long MB = 1048576;

    char* ws = (char*)d_ws;
    // weights (persistent until consumed):
    u16* WT   = (u16*)(ws + 0*MB);    // QKVG combined (6144,1024)  12 MB [..QKVG gemm]
    u16* WOT  = (u16*)(ws + 12*MB);   // (1024, 2048)                4 MB [..WO]
    u16* fw1T = (u16*)(ws + 16*MB);   // (4096, 1024)                8 MB [..FFN1]
    u16* fw2T = (u16*)(ws + 24*MB);   // (1024, 4096)                8 MB [..FFN2]
    // activations:
    u16*   QKVG = (u16*)(ws + 32*MB); // bf16 (B,S,6144) 48 MB [QKVG gemm .. WO]
                                      //   V segment row-major unused (V goes straight to Vt);
                                      //   WO parks fp32 partials in Q/K/V seg bytes of each row
    u16*   Xn   = (u16*)(ws + 80*MB); // bf16 (B,S,D)     8 MB [prep .. QKVG gemm]
    float4* xtab= (float4*)(ws + 88*MB);// fp32 table     2 MB [prep .. QKVG gemm]
    u16*   Vt   = (u16*)(ws + 90*MB); // bf16 (B,H,256,S)16 MB [QKVG gemm .. retention]
    float* X2   = (float*)(ws + 80*MB);//fp32 (B,S,D)    16 MB [ln2_combine .. ffn2_combine] (reuses Xn+xtab+Vt head)
    u16*   hb   = (u16*)(ws + 0*MB);  // bf16 (B,S,D)     8 MB [ln2_combine .. FFN1] (reuses WT)
    u16*   mid  = (u16*)(ws + 32*MB); // bf16 (B,S,FFN)  32 MB [FFN1 .. FFN2]        (reuses QKVG)
    float* PF   = (float*)(ws + 0*MB);// FFN2 partials: P0 [0,16), P1 [64,80) MB

    // 1. fused prep: 7x weight transpose + xPos table + LN1
    prep_k<<<20992, 256, 0, stream>>>(Wq, Wk, Wv, WG, WO, fw1, fw2, X, ln1w, ln1b,
                                      WT, WOT, fw1T, fw2T, xtab, Xn);
    // 2. fused QKVG projection + xPos epilogue; V blocks stored transposed into Vt
    //    [BK=32 dbuf ring]
    mgemm<EPI_QKVG><<<1536, 256, 0, stream>>>(
        Xn, WT, QKVG, D, D, 6144, (const float*)xtab, Vt);
    // 3. retention + groupnorm + silu-gate -> in-place on G segment [LDS swizzled]
    retention_mfma<<<512, 256, 0, stream>>>(QKVG, Vt, gnw, gnb);
    // 4. WO split-K x2: partials into dead Q/K/V segment bytes of QKVG rows  [BK=64, dbuf ring]
    mgemm_sk<<<512, 256, 0, stream>>>(
        QKVG + 4096, WOT, (float*)QKVG, 2048, 1024, 6144, 3072, 1024);
    // 5. combine + residual + LN2 -> X2 (fp32) and hb (bf16)
    ln2_combine<<<M, 256, 0, stream>>>((const float*)QKVG, X, ln2w, ln2b, X2, hb);
    // 6. mid = gelu_fast(hb @ W1 + b1)  bf16  [BK=32 dbuf ring]
    mgemm<EPI_GELU_BIAS><<<1024, 256, 0, stream>>>(
        hb, fw1T, mid, D, D, FFN, fb1, nullptr);
    // 7. FFN2 split-K x2: partials P0 [0,16), P1 [64,80) MB  [BK=64, dbuf ring]
    mgemm_sk<<<512, 256, 0, stream>>>(
        mid, fw2T, PF, 4096, 2048, 4096, 1024, 16777216);
    // 8. combine + bias + X2 residual -> d_out (fp32)
    ffn2_combine<<<M, 256, 0, stream>>>(PF, fb2, X2, (float*)d_out);
}